// Round 11
// baseline (1331.380 us; speedup 1.0000x reference)
//
#include <hip/hip_runtime.h>
#include <hip/hip_bf16.h>
#include <stdint.h>

typedef __attribute__((ext_vector_type(4))) float f32x4;
typedef __attribute__((ext_vector_type(8))) short short8;
typedef __attribute__((ext_vector_type(4))) short short4v;

#define CDIV(a, b) (((a) + (b) - 1) / (b))

__device__ __forceinline__ unsigned short f2bf(float x) {
  union { float f; unsigned int u; } c; c.f = x;
  unsigned int r = c.u + 0x7FFFu + ((c.u >> 16) & 1u);   // round-to-nearest-even
  return (unsigned short)(r >> 16);
}
__device__ __forceinline__ unsigned short f2bf_hw(float x) {
  __hip_bfloat16 h = __float2bfloat16(x);                // pairs fuse into v_cvt_pk_bf16_f32
  unsigned short u; __builtin_memcpy(&u, &h, 2); return u;
}
__device__ __forceinline__ float bf2f(unsigned short b) {
  union { unsigned int u; float f; } c; c.u = (unsigned int)b << 16; return c.f;
}

// async global->LDS, 16B per lane; LDS dest must be wave-uniform base + lane*16 (linear)
__device__ __forceinline__ void gl2lds16(const void* g, void* lds) {
  __builtin_amdgcn_global_load_lds(
      reinterpret_cast<const __attribute__((address_space(1))) unsigned int*>(
          reinterpret_cast<uintptr_t>(g)),
      reinterpret_cast<__attribute__((address_space(3))) unsigned int*>(
          reinterpret_cast<uintptr_t>(lds)),
      16, 0, 0);
}

// ---------------- weight transpose: W[K][N] f32 -> Wt[N][Kpad] bf16, zero-padded ----------------
__global__ void transpose_w(const float* __restrict__ W, unsigned short* __restrict__ Wt,
                            int K, int N, int Kpad) {
  __shared__ float tile[32][33];
  int kb = blockIdx.x * 32, nb = blockIdx.y * 32;
  int tx = threadIdx.x & 31, ty = threadIdx.x >> 5;  // 256 threads = 32x8
  for (int r = ty; r < 32; r += 8) {
    int k = kb + r, n = nb + tx;
    tile[r][tx] = (k < K && n < N) ? W[(size_t)k * N + n] : 0.f;
  }
  __syncthreads();
  for (int r = ty; r < 32; r += 8) {
    int n = nb + r, k = kb + tx;
    if (n < N && k < Kpad) Wt[(size_t)n * Kpad + k] = f2bf(tile[tx][r]);
  }
}

// ---------------- graph prep ----------------
__global__ void zero_i32(int* __restrict__ p, int n) {
  int i = blockIdx.x * blockDim.x + threadIdx.x;
  if (i < n) p[i] = 0;
}

__global__ void deg_init(int* __restrict__ a, int* __restrict__ b, int n) {
  int i = blockIdx.x * blockDim.x + threadIdx.x;
  if (i < n) { a[i] = 1; b[i] = 1; }   // self-loop
}

__global__ void deg_hist(const int* __restrict__ ei, int E, int* __restrict__ deg, int n) {
  int e = blockIdx.x * blockDim.x + threadIdx.x;
  if (e >= E) return;
  unsigned int d = (unsigned int)ei[(size_t)E + e];
  if (d < (unsigned int)n) atomicAdd(&deg[d], 1);
}

__global__ void dinv_k(const int* __restrict__ deg, float* __restrict__ dinv, int n) {
  int i = blockIdx.x * blockDim.x + threadIdx.x;
  if (i < n) dinv[i] = rsqrtf((float)deg[i]);
}

// exclusive scan of (deg-1) -> row_ptr[0..n], single block of 1024, shfl-based
__global__ void scan_rowptr(const int* __restrict__ deg, int* __restrict__ rp, int n) {
  __shared__ int wsum[16];
  __shared__ int carry_s;
  const int tid = threadIdx.x, lane = tid & 63, w = tid >> 6;
  if (tid == 0) carry_s = 0;
  __syncthreads();
  for (int base = 0; base < n; base += 1024) {
    int i = base + tid;
    int d = (i < n) ? (deg[i] - 1) : 0;
    int v = d;
    #pragma unroll
    for (int off = 1; off < 64; off <<= 1) {
      int t = __shfl_up(v, off, 64);
      if (lane >= off) v += t;
    }
    if (lane == 63) wsum[w] = v;
    __syncthreads();
    int carry = carry_s;
    if (w == 0) {
      int s = (lane < 16) ? wsum[lane] : 0;
      #pragma unroll
      for (int off = 1; off < 16; off <<= 1) {
        int t = __shfl_up(s, off, 64);
        if (lane >= off) s += t;
      }
      if (lane < 16) wsum[lane] = s;
    }
    __syncthreads();
    int woff = (w > 0) ? wsum[w - 1] : 0;
    if (i < n) rp[i] = carry + woff + v - d;
    if (tid == 0) carry_s = carry + wsum[15];
    __syncthreads();
  }
  if (threadIdx.x == 0) rp[n] = carry_s;
}

__global__ void csr_fill(const int* __restrict__ ei, int E,
                         const int* __restrict__ row_ptr, int* __restrict__ cursor,
                         const float* __restrict__ dinv,
                         int* __restrict__ csr_src, float* __restrict__ csr_nrm, int n) {
  int e = blockIdx.x * blockDim.x + threadIdx.x;
  if (e >= E) return;
  unsigned int s = (unsigned int)ei[e];
  unsigned int d = (unsigned int)ei[(size_t)E + e];
  if (s >= (unsigned int)n || d >= (unsigned int)n) return;
  int pos = row_ptr[d] + atomicAdd(&cursor[d], 1);
  csr_src[pos] = (int)s;
  csr_nrm[pos] = dinv[s] * dinv[d];
}

// ---------------- fc_gemm: A-DIRECT register GEMM for f32-A FC layers ----------------
// BM=256, BN=128, TH=256 (4 waves, FM=4, FN=8). A fragments loaded lane-direct from
// global (f32, cvt to bf16 in-register), double-buffered across K-steps; only the tiny
// B tile (16 KB, L2-hot) goes through LDS (double-buffered). Barrier drain waits only
// on loads issued a full compute-phase earlier -> effectively free.
template<int NT_N, bool ADD_BIAS, bool DO_RELU>
__global__ __launch_bounds__(256, 2)
void fc_gemm(const float* __restrict__ A, const unsigned short* __restrict__ Bt,
             const float* __restrict__ bias, unsigned short* __restrict__ C,
             int NT_M, int M, int N, int K, int Kpad) {
  constexpr int BM = 256, BN = 128, BK = 64, TH = 256;
  constexpr int FM = 4, FN = 8;
  constexpr int BIT = (BN * 8) / TH;   // 4 gl2lds per thread
  constexpr int LOGN = (NT_N == 4) ? 2 : (NT_N == 2 ? 1 : 0);

  const int bid = blockIdx.x;
  const int xcd = bid & 7, j = bid >> 3;
  const int per = (NT_M + 7) >> 3;
  const int mt = xcd * per + (j >> LOGN);
  const int nt = j & (NT_N - 1);
  if (mt >= NT_M) return;
  const int gm = mt * BM, gn = nt * BN;

  __shared__ __align__(16) unsigned short Blds[2][BN * BK];   // 2 x 16 KB

  const int tid = threadIdx.x;
  const int wm = tid >> 6, lane = tid & 63;
  const int kg = lane >> 4, lr = lane & 15;
  const int sx = lr & 7;

  const float* aptr[FM];
  #pragma unroll
  for (int m = 0; m < FM; m++) {
    int r = gm + wm * 64 + m * 16 + lr;
    if (r > M - 1) r = M - 1;
    aptr[m] = A + (size_t)r * K;
  }

  f32x4 acc[FM][FN] = {};
  f32x4 areg[FM][2][2];   // [m][ks][half] : in-flight A for next step (f32)

  auto issueA = [&](int k0) {
    #pragma unroll
    for (int m = 0; m < FM; m++)
      #pragma unroll
      for (int ks = 0; ks < 2; ks++) {
        int kb = k0 + ks * 32 + kg * 8;
        int kc = (kb + 8 <= K) ? kb : (K - 8);   // clamp (tail zero-masked at cvt)
        areg[m][ks][0] = *(const f32x4*)(aptr[m] + kc);
        areg[m][ks][1] = *(const f32x4*)(aptr[m] + kc + 4);
      }
  };
  auto stageB = [&](int buf, int k0) {
    #pragma unroll
    for (int it = 0; it < BIT; ++it) {
      int q = it * TH + tid;
      int r = q >> 3, s = q & 7;
      gl2lds16(Bt + (size_t)(gn + r) * Kpad + k0 + ((s ^ (r & 7)) << 3), &Blds[buf][q * 8]);
    }
  };

  // prologue
  issueA(0);
  stageB(0, 0);
  asm volatile("s_waitcnt vmcnt(0)" ::: "memory");
  __builtin_amdgcn_sched_barrier(0);
  __builtin_amdgcn_s_barrier();

  const int nkt = Kpad / BK;
  int p = 0;
  for (int kt = 0; kt < nkt; ++kt) {
    const int k0 = kt * BK;
    // ---- cvt landed A regs -> bf16 fragments (zero-mask K tail; K%8==0) ----
    short8 abf[FM][2];
    #pragma unroll
    for (int m = 0; m < FM; m++) {
      #pragma unroll
      for (int ks = 0; ks < 2; ks++) {
        int kb = k0 + ks * 32 + kg * 8;
        short8 b;
        #pragma unroll
        for (int i = 0; i < 4; i++) {
          b[i]     = (short)f2bf_hw(areg[m][ks][0][i]);
          b[i + 4] = (short)f2bf_hw(areg[m][ks][1][i]);
        }
        if (kb + 8 > K) {
          #pragma unroll
          for (int i = 0; i < 8; i++) b[i] = 0;
        }
        abf[m][ks] = b;
      }
    }
    // ---- prefetch step t+1 (A regs now free; B into other LDS buffer) ----
    if (kt + 1 < nkt) {
      issueA(k0 + BK);
      stageB(p ^ 1, k0 + BK);
    }
    // ---- compute step t ----
    #pragma unroll
    for (int ks = 0; ks < 2; ks++) {
      const int k8 = ks * 4 + kg;
      #pragma unroll
      for (int n2 = 0; n2 < FN; n2++) {
        int cc = n2 * 16 + lr;
        short8 bq = *(const short8*)(&Blds[p][(cc * 8 + (k8 ^ sx)) * 8]);
        #pragma unroll
        for (int m = 0; m < FM; m++)
          acc[m][n2] = __builtin_amdgcn_mfma_f32_16x16x32_bf16(abf[m][ks], bq, acc[m][n2], 0, 0, 0);
      }
    }
    // ---- drain (loads had full compute phase to land) + publish Blds[p^1] ----
    asm volatile("s_waitcnt vmcnt(0)" ::: "memory");
    __builtin_amdgcn_sched_barrier(0);
    __builtin_amdgcn_s_barrier();
    p ^= 1;
  }
  // ---- epilogue: C/D layout col=lane&15, row=(lane>>4)*4+reg ----
  #pragma unroll
  for (int m = 0; m < FM; m++) {
    #pragma unroll
    for (int jj = 0; jj < 4; jj++) {
      int grow = gm + wm * 64 + m * 16 + kg * 4 + jj;
      if (grow < M) {
        #pragma unroll
        for (int n2 = 0; n2 < FN; n2++) {
          int gcol = gn + n2 * 16 + lr;
          float v = acc[m][n2][jj];
          if constexpr (ADD_BIAS) v += bias[gcol];
          if constexpr (DO_RELU) v = fmaxf(v, 0.f);
          C[(size_t)grow * N + gcol] = f2bf(v);
        }
      }
    }
  }
}

// ---------------- gemm7: BM=64 mid-size GEMM (bf16 A), r8-proven config ----
template<int BM, int BN, int TH, int NT_N, bool ADD_BIAS, bool DO_RELU>
__global__ __launch_bounds__(TH, 2)
void gemm7(const unsigned short* __restrict__ A, const unsigned short* __restrict__ Bt,
           const float* __restrict__ bias, unsigned short* __restrict__ C,
           int NT_M, int M, int N, int K, int Kpad) {
  constexpr int BK = 64;
  constexpr int WN = TH / 64;
  constexpr int WCOLS = BN / WN;
  constexpr int FM = BM / 16, FN = WCOLS / 16;
  constexpr int BIT = (BN * 8) / TH;
  constexpr int AIT = (BM * 8) / TH;
  constexpr int LOGN = (NT_N == 2) ? 1 : 0;

  const int bid = blockIdx.x;
  const int xcd = bid & 7, j = bid >> 3;
  const int per = (NT_M + 7) >> 3;
  const int mt = xcd * per + (j >> LOGN);
  const int nt = j & (NT_N - 1);
  if (mt >= NT_M) return;
  const int gm = mt * BM, gn = nt * BN;

  __shared__ __align__(16) unsigned short Alds[BM * BK];
  __shared__ __align__(16) unsigned short Blds[BN * BK];

  const int tid = threadIdx.x;
  const int wid = tid >> 6, lane = tid & 63;
  const int kg = lane >> 4, lr = lane & 15;
  const int sx = lr & 7;

  f32x4 acc[FM][FN] = {};

  const int nkt = Kpad / BK;
  for (int kt = 0; kt < nkt; ++kt) {
    const int k0 = kt * BK;
    #pragma unroll
    for (int it = 0; it < AIT; ++it) {
      int q = it * TH + tid;
      int r = q >> 3, s = q & 7;
      int grow = gm + r; if (grow > M - 1) grow = M - 1;
      gl2lds16(A + (size_t)grow * K + k0 + ((s ^ (r & 7)) << 3), &Alds[q * 8]);
    }
    #pragma unroll
    for (int it = 0; it < BIT; ++it) {
      int q = it * TH + tid;
      int r = q >> 3, s = q & 7;
      gl2lds16(Bt + (size_t)(gn + r) * Kpad + k0 + ((s ^ (r & 7)) << 3), &Blds[q * 8]);
    }
    __syncthreads();
    #pragma unroll
    for (int ks = 0; ks < 2; ++ks) {
      const int k8 = ks * 4 + kg;
      short8 af[FM];
      #pragma unroll
      for (int m = 0; m < FM; m++) {
        int r = m * 16 + lr;
        af[m] = *(const short8*)(&Alds[(r * 8 + (k8 ^ sx)) * 8]);
      }
      #pragma unroll
      for (int n2 = 0; n2 < FN; n2++) {
        int cc = wid * WCOLS + n2 * 16 + lr;
        short8 bq = *(const short8*)(&Blds[(cc * 8 + (k8 ^ sx)) * 8]);
        #pragma unroll
        for (int m = 0; m < FM; m++)
          acc[m][n2] = __builtin_amdgcn_mfma_f32_16x16x32_bf16(af[m], bq, acc[m][n2], 0, 0, 0);
      }
    }
    __syncthreads();
  }
  #pragma unroll
  for (int m = 0; m < FM; m++) {
    #pragma unroll
    for (int jj = 0; jj < 4; jj++) {
      int grow = gm + m * 16 + kg * 4 + jj;
      if (grow < M) {
        #pragma unroll
        for (int n2 = 0; n2 < FN; n2++) {
          int gcol = gn + wid * WCOLS + n2 * 16 + lr;
          float v = acc[m][n2][jj];
          if constexpr (ADD_BIAS) v += bias[gcol];
          if constexpr (DO_RELU) v = fmaxf(v, 0.f);
          C[(size_t)grow * N + gcol] = f2bf(v);
        }
      }
    }
  }
}

// ---------------- fused dual-graph GCN scatter ----------------
// out = w * act(gcnA(hA)+bA) + (1-w) * act(gcnB(hB)+bB), act = relu or identity.
template<int F, int LDHA, int LDHB, bool DO_RELU, bool OUT_BF16>
__global__ __launch_bounds__(256)
void scatter_fused(const unsigned short* __restrict__ hA, const unsigned short* __restrict__ hB,
                   const int* __restrict__ rpA, const int* __restrict__ csA,
                   const float* __restrict__ cnA, const float* __restrict__ dvA,
                   const float* __restrict__ bA,
                   const int* __restrict__ rpB, const int* __restrict__ csB,
                   const float* __restrict__ cnB, const float* __restrict__ dvB,
                   const float* __restrict__ bB,
                   const float* __restrict__ wptr, void* __restrict__ outp, int n) {
  constexpr int TPN = F / 4;
  const int tid = threadIdx.x;
  const int node = blockIdx.x * (256 / TPN) + tid / TPN;
  const int c4 = (tid % TPN) * 4;
  if (node >= n) return;

  f32x4 accA, accB, t2 = {0.f, 0.f, 0.f, 0.f};
  {
    float d = dvA[node]; float sc = d * d;
    short4v v = *(const short4v*)(hA + (size_t)node * LDHA + c4);
    accA[0] = sc * bf2f((unsigned short)v[0]);
    accA[1] = sc * bf2f((unsigned short)v[1]);
    accA[2] = sc * bf2f((unsigned short)v[2]);
    accA[3] = sc * bf2f((unsigned short)v[3]);
    const int e1 = rpA[node + 1];
    int e = rpA[node];
    for (; e + 2 <= e1; e += 2) {
      int s0 = csA[e], s1 = csA[e + 1];
      float n0 = cnA[e], n1 = cnA[e + 1];
      short4v v0 = *(const short4v*)(hA + (size_t)s0 * LDHA + c4);
      short4v v1 = *(const short4v*)(hA + (size_t)s1 * LDHA + c4);
      accA[0] += n0 * bf2f((unsigned short)v0[0]); t2[0] += n1 * bf2f((unsigned short)v1[0]);
      accA[1] += n0 * bf2f((unsigned short)v0[1]); t2[1] += n1 * bf2f((unsigned short)v1[1]);
      accA[2] += n0 * bf2f((unsigned short)v0[2]); t2[2] += n1 * bf2f((unsigned short)v1[2]);
      accA[3] += n0 * bf2f((unsigned short)v0[3]); t2[3] += n1 * bf2f((unsigned short)v1[3]);
    }
    if (e < e1) {
      int s0 = csA[e]; float n0 = cnA[e];
      short4v v0 = *(const short4v*)(hA + (size_t)s0 * LDHA + c4);
      accA[0] += n0 * bf2f((unsigned short)v0[0]);
      accA[1] += n0 * bf2f((unsigned short)v0[1]);
      accA[2] += n0 * bf2f((unsigned short)v0[2]);
      accA[3] += n0 * bf2f((unsigned short)v0[3]);
    }
    #pragma unroll
    for (int i = 0; i < 4; i++) { accA[i] += t2[i]; t2[i] = 0.f; }
  }
  {
    float d = dvB[node]; float sc = d * d;
    short4v v = *(const short4v*)(hB + (size_t)node * LDHB + c4);
    accB[0] = sc * bf2f((unsigned short)v[0]);
    accB[1] = sc * bf2f((unsigned short)v[1]);
    accB[2] = sc * bf2f((unsigned short)v[2]);
    accB[3] = sc * bf2f((unsigned short)v[3]);
    const int e1 = rpB[node + 1];
    int e = rpB[node];
    for (; e + 2 <= e1; e += 2) {
      int s0 = csB[e], s1 = csB[e + 1];
      float n0 = cnB[e], n1 = cnB[e + 1];
      short4v v0 = *(const short4v*)(hB + (size_t)s0 * LDHB + c4);
      short4v v1 = *(const short4v*)(hB + (size_t)s1 * LDHB + c4);
      accB[0] += n0 * bf2f((unsigned short)v0[0]); t2[0] += n1 * bf2f((unsigned short)v1[0]);
      accB[1] += n0 * bf2f((unsigned short)v0[1]); t2[1] += n1 * bf2f((unsigned short)v1[1]);
      accB[2] += n0 * bf2f((unsigned short)v0[2]); t2[2] += n1 * bf2f((unsigned short)v1[2]);
      accB[3] += n0 * bf2f((unsigned short)v0[3]); t2[3] += n1 * bf2f((unsigned short)v1[3]);
    }
    if (e < e1) {
      int s0 = csB[e]; float n0 = cnB[e];
      short4v v0 = *(const short4v*)(hB + (size_t)s0 * LDHB + c4);
      accB[0] += n0 * bf2f((unsigned short)v0[0]);
      accB[1] += n0 * bf2f((unsigned short)v0[1]);
      accB[2] += n0 * bf2f((unsigned short)v0[2]);
      accB[3] += n0 * bf2f((unsigned short)v0[3]);
    }
    #pragma unroll
    for (int i = 0; i < 4; i++) accB[i] += t2[i];
  }
  f32x4 bvA = *(const f32x4*)(bA + c4);
  f32x4 bvB = *(const f32x4*)(bB + c4);
  float w = *wptr;
  size_t idx = (size_t)node * F + c4;
  f32x4 r;
  #pragma unroll
  for (int i = 0; i < 4; i++) {
    float va = accA[i] + bvA[i];
    float vb = accB[i] + bvB[i];
    if constexpr (DO_RELU) { va = fmaxf(va, 0.f); vb = fmaxf(vb, 0.f); }
    r[i] = w * va + (1.f - w) * vb;
  }
  if constexpr (OUT_BF16) {
    short4v o;
    o[0] = (short)f2bf(r[0]); o[1] = (short)f2bf(r[1]);
    o[2] = (short)f2bf(r[2]); o[3] = (short)f2bf(r[3]);
    *(short4v*)((unsigned short*)outp + idx) = o;
  } else {
    *(f32x4*)((float*)outp + idx) = r;
  }
}

// ---------------- host ----------------
extern "C" void kernel_launch(void* const* d_in, const int* in_sizes, int n_in,
                              void* d_out, int out_size, void* d_ws, size_t ws_size,
                              hipStream_t stream) {
  const float* gene  = (const float*)d_in[0];
  const float* img   = (const float*)d_in[1];
  const int* ei_ge = (const int*)d_in[2];   // integers arrive as int32
  const int* ei_sp = (const int*)d_in[3];
  const float* W_fc1 = (const float*)d_in[4];  const float* b_fc1 = (const float*)d_in[5];
  const float* W_fc2 = (const float*)d_in[6];  const float* b_fc2 = (const float*)d_in[7];
  const float* W_g11 = (const float*)d_in[8];  const float* b_g11 = (const float*)d_in[9];
  const float* W_g12 = (const float*)d_in[10]; const float* b_g12 = (const float*)d_in[11];
  const float* W_g21 = (const float*)d_in[12]; const float* b_g21 = (const float*)d_in[13];
  const float* W_g22 = (const float*)d_in[14]; const float* b_g22 = (const float*)d_in[15];
  const float* w1p   = (const float*)d_in[16];
  const float* w2p   = (const float*)d_in[17];

  const int Nn = 50000;
  const int E_ge = in_sizes[2] / 2;
  const int E_sp = in_sizes[3] / 2;

  const int NT_MF = CDIV(Nn, 256);           // 196 M-tiles of 256 (fc_gemm)
  const int GF    = 8 * CDIV(NT_MF, 8) * 4;  // NT_N=4 -> 800 blocks
  const int NT_M7 = CDIV(Nn, 64);            // 782 M-tiles of 64 (gemm7)
  const int G7    = 8 * CDIV(NT_M7, 8);      // 784 blocks

  char* ws = (char*)d_ws;
  size_t off = 0;
  auto alloc = [&](size_t bytes) -> void* {
    void* p = ws + off;
    off += (bytes + 255) & ~(size_t)255;
    return p;
  };

  unsigned short* Wt1  = (unsigned short*)alloc((size_t)512 * 3008 * 2);
  unsigned short* Wt2  = (unsigned short*)alloc((size_t)512 * 1024 * 2);
  unsigned short* Wt11 = (unsigned short*)alloc((size_t)256 * 512 * 2);
  unsigned short* Wt12 = (unsigned short*)alloc((size_t)256 * 512 * 2);
  unsigned short* WtC  = (unsigned short*)alloc((size_t)128 * 256 * 2);  // [W_g21 | W_g22] rows
  int*   deg_sp  = (int*)alloc((size_t)Nn * 4);
  int*   deg_ge  = (int*)alloc((size_t)Nn * 4);
  float* dinv_sp = (float*)alloc((size_t)Nn * 4);
  float* dinv_ge = (float*)alloc((size_t)Nn * 4);
  int*   rp_sp   = (int*)alloc((size_t)(Nn + 1) * 4);
  int*   rp_ge   = (int*)alloc((size_t)(Nn + 1) * 4);
  int*   cursor  = (int*)alloc((size_t)Nn * 4);
  int*   csrc_sp = (int*)alloc((size_t)E_sp * 4);
  float* cnrm_sp = (float*)alloc((size_t)E_sp * 4);
  int*   csrc_ge = (int*)alloc((size_t)E_ge * 4);
  float* cnrm_ge = (float*)alloc((size_t)E_ge * 4);
  unsigned short* xbuf = (unsigned short*)alloc((size_t)Nn * 512 * 2);  // x1 / x2 / Xc
  unsigned short* tmpA = (unsigned short*)alloc((size_t)Nn * 256 * 2);  // g11 out; later tmp2
  unsigned short* tmpB = (unsigned short*)alloc((size_t)Nn * 256 * 2);  // g12 out
  unsigned short* Xc   = xbuf;
  unsigned short* tmp2 = tmpA;
  (void)ws_size; (void)n_in; (void)out_size;

  // 1. weight transposes (bf16, K zero-padded)
  transpose_w<<<dim3(94, 16), 256, 0, stream>>>(W_fc1, Wt1, 3000, 512, 3008);
  transpose_w<<<dim3(32, 16), 256, 0, stream>>>(W_fc2, Wt2, 1024, 512, 1024);
  transpose_w<<<dim3(16, 8),  256, 0, stream>>>(W_g11, Wt11, 512, 256, 512);
  transpose_w<<<dim3(16, 8),  256, 0, stream>>>(W_g12, Wt12, 512, 256, 512);
  transpose_w<<<dim3(8, 2),   256, 0, stream>>>(W_g21, WtC, 256, 64, 256);
  transpose_w<<<dim3(8, 2),   256, 0, stream>>>(W_g22, WtC + (size_t)64 * 256, 256, 64, 256);

  // 2. graph prep
  deg_init<<<CDIV(Nn, 256), 256, 0, stream>>>(deg_sp, deg_ge, Nn);
  deg_hist<<<CDIV(E_sp, 256), 256, 0, stream>>>(ei_sp, E_sp, deg_sp, Nn);
  deg_hist<<<CDIV(E_ge, 256), 256, 0, stream>>>(ei_ge, E_ge, deg_ge, Nn);
  dinv_k<<<CDIV(Nn, 256), 256, 0, stream>>>(deg_sp, dinv_sp, Nn);
  dinv_k<<<CDIV(Nn, 256), 256, 0, stream>>>(deg_ge, dinv_ge, Nn);
  scan_rowptr<<<1, 1024, 0, stream>>>(deg_sp, rp_sp, Nn);
  scan_rowptr<<<1, 1024, 0, stream>>>(deg_ge, rp_ge, Nn);
  zero_i32<<<CDIV(Nn, 256), 256, 0, stream>>>(cursor, Nn);
  csr_fill<<<CDIV(E_sp, 256), 256, 0, stream>>>(ei_sp, E_sp, rp_sp, cursor, dinv_sp, csrc_sp, cnrm_sp, Nn);
  zero_i32<<<CDIV(Nn, 256), 256, 0, stream>>>(cursor, Nn);
  csr_fill<<<CDIV(E_ge, 256), 256, 0, stream>>>(ei_ge, E_ge, rp_ge, cursor, dinv_ge, csrc_ge, cnrm_ge, Nn);

  // 3. x1 = relu(gene @ W_fc1 + b) -> bf16   (A-direct register GEMM)
  fc_gemm<4, true, true><<<GF, 256, 0, stream>>>(
      gene, Wt1, b_fc1, xbuf, NT_MF, Nn, 512, 3000, 3008);
  // 4. tmpA = x1 @ W_g11
  gemm7<64, 256, 256, 1, false, false><<<G7, 256, 0, stream>>>(
      xbuf, Wt11, nullptr, tmpA, NT_M7, Nn, 256, 512, 512);
  // 5. x2 = relu(img @ W_fc2 + b) -> bf16 (reuse xbuf; K=1024)
  fc_gemm<4, true, true><<<GF, 256, 0, stream>>>(
      img, Wt2, b_fc2, xbuf, NT_MF, Nn, 512, 1024, 1024);
  // 6. tmpB = x2 @ W_g12
  gemm7<64, 256, 256, 1, false, false><<<G7, 256, 0, stream>>>(
      xbuf, Wt12, nullptr, tmpB, NT_M7, Nn, 256, 512, 512);
  // 7. Xc = bf16( w1*relu(gcn_sp(tmpA)+b_g11) + (1-w1)*relu(gcn_ge(tmpB)+b_g12) )
  scatter_fused<256, 256, 256, true, true><<<Nn / 4, 256, 0, stream>>>(
      tmpA, tmpB, rp_sp, csrc_sp, cnrm_sp, dinv_sp, b_g11,
      rp_ge, csrc_ge, cnrm_ge, dinv_ge, b_g12, w1p, Xc, Nn);
  // 8. tmp2 = Xc @ [W_g21 | W_g22]  (N=128, one pass; tmp2 aliases tmpA)
  gemm7<64, 128, 256, 1, false, false><<<G7, 256, 0, stream>>>(
      Xc, WtC, nullptr, tmp2, NT_M7, Nn, 128, 256, 256);
  // 9. d_out = w2*(gcn_sp(tmp2[:,0:64])+b_g21) + (1-w2)*(gcn_ge(tmp2[:,64:128])+b_g22)
  scatter_fused<64, 128, 128, false, false><<<Nn / 16, 256, 0, stream>>>(
      tmp2, tmp2 + 64, rp_sp, csrc_sp, cnrm_sp, dinv_sp, b_g21,
      rp_ge, csrc_ge, cnrm_ge, dinv_ge, b_g22, w2p, d_out, Nn);
}

// Round 12
// 989.832 us; speedup vs baseline: 1.3451x; 1.3451x over previous
//
#include <hip/hip_runtime.h>
#include <hip/hip_bf16.h>
#include <stdint.h>

typedef __attribute__((ext_vector_type(4))) float f32x4;
typedef __attribute__((ext_vector_type(8))) short short8;
typedef __attribute__((ext_vector_type(4))) short short4v;

#define CDIV(a, b) (((a) + (b) - 1) / (b))

__device__ __forceinline__ unsigned short f2bf(float x) {
  union { float f; unsigned int u; } c; c.f = x;
  unsigned int r = c.u + 0x7FFFu + ((c.u >> 16) & 1u);   // round-to-nearest-even
  return (unsigned short)(r >> 16);
}
__device__ __forceinline__ unsigned short f2bf_hw(float x) {
  __hip_bfloat16 h = __float2bfloat16(x);                // pairs fuse into v_cvt_pk_bf16_f32
  unsigned short u; __builtin_memcpy(&u, &h, 2); return u;
}
__device__ __forceinline__ float bf2f(unsigned short b) {
  union { unsigned int u; float f; } c; c.u = (unsigned int)b << 16; return c.f;
}

// async global->LDS, 16B per lane; LDS dest must be wave-uniform base + lane*16 (linear)
__device__ __forceinline__ void gl2lds16(const void* g, void* lds) {
  __builtin_amdgcn_global_load_lds(
      reinterpret_cast<const __attribute__((address_space(1))) unsigned int*>(
          reinterpret_cast<uintptr_t>(g)),
      reinterpret_cast<__attribute__((address_space(3))) unsigned int*>(
          reinterpret_cast<uintptr_t>(lds)),
      16, 0, 0);
}

// ---------------- weight transpose: W[K][N] f32 -> Wt[N][Kpad] bf16, zero-padded ----------------
__global__ void transpose_w(const float* __restrict__ W, unsigned short* __restrict__ Wt,
                            int K, int N, int Kpad) {
  __shared__ float tile[32][33];
  int kb = blockIdx.x * 32, nb = blockIdx.y * 32;
  int tx = threadIdx.x & 31, ty = threadIdx.x >> 5;  // 256 threads = 32x8
  for (int r = ty; r < 32; r += 8) {
    int k = kb + r, n = nb + tx;
    tile[r][tx] = (k < K && n < N) ? W[(size_t)k * N + n] : 0.f;
  }
  __syncthreads();
  for (int r = ty; r < 32; r += 8) {
    int n = nb + r, k = kb + tx;
    if (n < N && k < Kpad) Wt[(size_t)n * Kpad + k] = f2bf(tile[tx][r]);
  }
}

// ---------------- graph prep ----------------
__global__ void zero_i32(int* __restrict__ p, int n) {
  int i = blockIdx.x * blockDim.x + threadIdx.x;
  if (i < n) p[i] = 0;
}

__global__ void deg_init(int* __restrict__ a, int* __restrict__ b, int n) {
  int i = blockIdx.x * blockDim.x + threadIdx.x;
  if (i < n) { a[i] = 1; b[i] = 1; }   // self-loop
}

__global__ void deg_hist(const int* __restrict__ ei, int E, int* __restrict__ deg, int n) {
  int e = blockIdx.x * blockDim.x + threadIdx.x;
  if (e >= E) return;
  unsigned int d = (unsigned int)ei[(size_t)E + e];
  if (d < (unsigned int)n) atomicAdd(&deg[d], 1);
}

__global__ void dinv_k(const int* __restrict__ deg, float* __restrict__ dinv, int n) {
  int i = blockIdx.x * blockDim.x + threadIdx.x;
  if (i < n) dinv[i] = rsqrtf((float)deg[i]);
}

// exclusive scan of (deg-1) -> row_ptr[0..n], single block of 1024, shfl-based
__global__ void scan_rowptr(const int* __restrict__ deg, int* __restrict__ rp, int n) {
  __shared__ int wsum[16];
  __shared__ int carry_s;
  const int tid = threadIdx.x, lane = tid & 63, w = tid >> 6;
  if (tid == 0) carry_s = 0;
  __syncthreads();
  for (int base = 0; base < n; base += 1024) {
    int i = base + tid;
    int d = (i < n) ? (deg[i] - 1) : 0;
    int v = d;
    #pragma unroll
    for (int off = 1; off < 64; off <<= 1) {
      int t = __shfl_up(v, off, 64);
      if (lane >= off) v += t;
    }
    if (lane == 63) wsum[w] = v;
    __syncthreads();
    int carry = carry_s;
    if (w == 0) {
      int s = (lane < 16) ? wsum[lane] : 0;
      #pragma unroll
      for (int off = 1; off < 16; off <<= 1) {
        int t = __shfl_up(s, off, 64);
        if (lane >= off) s += t;
      }
      if (lane < 16) wsum[lane] = s;
    }
    __syncthreads();
    int woff = (w > 0) ? wsum[w - 1] : 0;
    if (i < n) rp[i] = carry + woff + v - d;
    if (tid == 0) carry_s = carry + wsum[15];
    __syncthreads();
  }
  if (threadIdx.x == 0) rp[n] = carry_s;
}

__global__ void csr_fill(const int* __restrict__ ei, int E,
                         const int* __restrict__ row_ptr, int* __restrict__ cursor,
                         const float* __restrict__ dinv,
                         int* __restrict__ csr_src, float* __restrict__ csr_nrm, int n) {
  int e = blockIdx.x * blockDim.x + threadIdx.x;
  if (e >= E) return;
  unsigned int s = (unsigned int)ei[e];
  unsigned int d = (unsigned int)ei[(size_t)E + e];
  if (s >= (unsigned int)n || d >= (unsigned int)n) return;
  int pos = row_ptr[d] + atomicAdd(&cursor[d], 1);
  csr_src[pos] = (int)s;
  csr_nrm[pos] = dinv[s] * dinv[d];
}

// ---------------- gemm_dual: TWO independent GEMM jobs in one launch (job = bid&1) ----------------
// Doubles independent barrier domains per CU -> latency hiding across jobs.
// Body = r8-proven gemm7: BM=64, BK=64, single-buffered, stage->sync->MFMA->sync.
// AMODE 1: A bf16 via gl2lds. AMODE 3: A f32 RAW via gl2lds (16-slot XOR swizzle),
// bf16 cvt at fragment read; K-tail reg-staged masked (K%4==0).
template<int BM, int BN, int TH, int NT_N, int AMODE, bool ADD_BIAS, bool DO_RELU>
__global__ __launch_bounds__(TH, 2)
void gemm_dual(const void* __restrict__ A0, const unsigned short* __restrict__ Bt0,
               const float* __restrict__ b0, unsigned short* __restrict__ C0, int K0, int Kp0,
               const void* __restrict__ A1, const unsigned short* __restrict__ Bt1,
               const float* __restrict__ b1, unsigned short* __restrict__ C1, int K1, int Kp1,
               int NT_M, int M, int N) {
  constexpr int BK = 64;
  constexpr int WN = TH / 64;
  constexpr int WCOLS = BN / WN;
  constexpr int FM = BM / 16, FN = WCOLS / 16;
  constexpr int BIT  = (BN * 8) / TH;
  constexpr int AIT1 = (BM * 8) / TH;
  constexpr int AIT3 = (BM * 16) / TH;
  constexpr int LOGN = (NT_N == 2) ? 1 : 0;

  const int bid0 = blockIdx.x;
  const int job = bid0 & 1;
  const int bid = bid0 >> 1;
  const void* Av = job ? A1 : A0;
  const unsigned short* Bt = job ? Bt1 : Bt0;
  const float* bias = job ? b1 : b0;
  unsigned short* C = job ? C1 : C0;
  const int K = job ? K1 : K0;
  const int Kpad = job ? Kp1 : Kp0;

  const int xcd = bid & 7, j = bid >> 3;
  const int per = (NT_M + 7) >> 3;
  const int mt = xcd * per + (j >> LOGN);
  const int nt = j & (NT_N - 1);
  if (mt >= NT_M) return;
  const int gm = mt * BM, gn = nt * BN;

  constexpr int ABYTES = (AMODE == 3) ? BM * BK * 4 : BM * BK * 2;
  __shared__ __align__(16) char AldsRaw[ABYTES];
  __shared__ __align__(16) unsigned short Blds[BN * BK];

  const int tid = threadIdx.x;
  const int wid = tid >> 6, lane = tid & 63;
  const int kg = lane >> 4, lr = lane & 15;
  const int sx = lr & 7;

  f32x4 acc[FM][FN] = {};

  const int nkt = Kpad / BK;
  for (int kt = 0; kt < nkt; ++kt) {
    const int k0 = kt * BK;
    // ---- stage A ----
    if constexpr (AMODE == 1) {
      const unsigned short* A = (const unsigned short*)Av;
      unsigned short* Alds = (unsigned short*)AldsRaw;
      #pragma unroll
      for (int it = 0; it < AIT1; ++it) {
        int q = it * TH + tid;
        int r = q >> 3, s = q & 7;
        int grow = gm + r; if (grow > M - 1) grow = M - 1;
        gl2lds16(A + (size_t)grow * K + k0 + ((s ^ (r & 7)) << 3), &Alds[q * 8]);
      }
    } else {  // AMODE 3: raw f32, 16 slots/row, swizzled source
      const float* A = (const float*)Av;
      float* Af = (float*)AldsRaw;
      if (k0 + BK <= K) {
        #pragma unroll
        for (int it = 0; it < AIT3; ++it) {
          int q = it * TH + tid;
          int r = q >> 4, s = q & 15;
          int grow = gm + r; if (grow > M - 1) grow = M - 1;
          gl2lds16(A + (size_t)grow * K + k0 + ((s ^ (r & 15)) << 2), &Af[q * 4]);
        }
      } else {  // tail (K%4==0): reg-staged, zero-masked
        #pragma unroll
        for (int it = 0; it < AIT3; ++it) {
          int q = it * TH + tid;
          int r = q >> 4, s = q & 15;
          int grow = gm + r; if (grow > M - 1) grow = M - 1;
          int kbase = k0 + ((s ^ (r & 15)) << 2);
          f32x4 v = {0.f, 0.f, 0.f, 0.f};
          if (kbase + 4 <= K) v = *(const f32x4*)(A + (size_t)grow * K + kbase);
          *(f32x4*)(&Af[q * 4]) = v;
        }
      }
    }
    // ---- stage B via gl2lds (linear dest, inverse-swizzled source) ----
    #pragma unroll
    for (int it = 0; it < BIT; ++it) {
      int q = it * TH + tid;
      int r = q >> 3, s = q & 7;
      gl2lds16(Bt + (size_t)(gn + r) * Kpad + k0 + ((s ^ (r & 7)) << 3), &Blds[q * 8]);
    }
    __syncthreads();
    // ---- fragments + MFMA (2 K-slices of 32) ----
    #pragma unroll
    for (int ks = 0; ks < 2; ++ks) {
      const int k8 = ks * 4 + kg;
      short8 af[FM];
      #pragma unroll
      for (int m = 0; m < FM; m++) {
        int r = m * 16 + lr;
        if constexpr (AMODE == 1) {
          const unsigned short* Alds = (const unsigned short*)AldsRaw;
          af[m] = *(const short8*)(&Alds[(r * 8 + (k8 ^ sx)) * 8]);
        } else {
          const float* Af = (const float*)AldsRaw;
          int s0 = (2 * k8) ^ lr, s1 = (2 * k8 + 1) ^ lr;
          f32x4 lo = *(const f32x4*)(Af + r * 64 + s0 * 4);
          f32x4 hi = *(const f32x4*)(Af + r * 64 + s1 * 4);
          #pragma unroll
          for (int i = 0; i < 4; i++) {
            af[m][i]     = (short)f2bf_hw(lo[i]);
            af[m][i + 4] = (short)f2bf_hw(hi[i]);
          }
        }
      }
      #pragma unroll
      for (int n2 = 0; n2 < FN; n2++) {
        int cc = wid * WCOLS + n2 * 16 + lr;
        short8 bq = *(const short8*)(&Blds[(cc * 8 + (k8 ^ sx)) * 8]);
        #pragma unroll
        for (int m = 0; m < FM; m++)
          acc[m][n2] = __builtin_amdgcn_mfma_f32_16x16x32_bf16(af[m], bq, acc[m][n2], 0, 0, 0);
      }
    }
    __syncthreads();
  }
  // ---- epilogue: C/D layout col=lane&15, row=(lane>>4)*4+reg ----
  #pragma unroll
  for (int m = 0; m < FM; m++) {
    #pragma unroll
    for (int jj = 0; jj < 4; jj++) {
      int grow = gm + m * 16 + kg * 4 + jj;
      if (grow < M) {
        #pragma unroll
        for (int n2 = 0; n2 < FN; n2++) {
          int gcol = gn + wid * WCOLS + n2 * 16 + lr;
          float v = acc[m][n2][jj];
          if constexpr (ADD_BIAS) v += bias[gcol];
          if constexpr (DO_RELU) v = fmaxf(v, 0.f);
          C[(size_t)grow * N + gcol] = f2bf(v);
        }
      }
    }
  }
}

// ---------------- gemm7: single-job BM=64 GEMM (bf16 A), r8-proven config ----------------
template<int BM, int BN, int TH, int NT_N, bool ADD_BIAS, bool DO_RELU>
__global__ __launch_bounds__(TH, 2)
void gemm7(const unsigned short* __restrict__ A, const unsigned short* __restrict__ Bt,
           const float* __restrict__ bias, unsigned short* __restrict__ C,
           int NT_M, int M, int N, int K, int Kpad) {
  constexpr int BK = 64;
  constexpr int WN = TH / 64;
  constexpr int WCOLS = BN / WN;
  constexpr int FM = BM / 16, FN = WCOLS / 16;
  constexpr int BIT = (BN * 8) / TH;
  constexpr int AIT = (BM * 8) / TH;
  constexpr int LOGN = (NT_N == 2) ? 1 : 0;

  const int bid = blockIdx.x;
  const int xcd = bid & 7, j = bid >> 3;
  const int per = (NT_M + 7) >> 3;
  const int mt = xcd * per + (j >> LOGN);
  const int nt = j & (NT_N - 1);
  if (mt >= NT_M) return;
  const int gm = mt * BM, gn = nt * BN;

  __shared__ __align__(16) unsigned short Alds[BM * BK];
  __shared__ __align__(16) unsigned short Blds[BN * BK];

  const int tid = threadIdx.x;
  const int wid = tid >> 6, lane = tid & 63;
  const int kg = lane >> 4, lr = lane & 15;
  const int sx = lr & 7;

  f32x4 acc[FM][FN] = {};

  const int nkt = Kpad / BK;
  for (int kt = 0; kt < nkt; ++kt) {
    const int k0 = kt * BK;
    #pragma unroll
    for (int it = 0; it < AIT; ++it) {
      int q = it * TH + tid;
      int r = q >> 3, s = q & 7;
      int grow = gm + r; if (grow > M - 1) grow = M - 1;
      gl2lds16(A + (size_t)grow * K + k0 + ((s ^ (r & 7)) << 3), &Alds[q * 8]);
    }
    #pragma unroll
    for (int it = 0; it < BIT; ++it) {
      int q = it * TH + tid;
      int r = q >> 3, s = q & 7;
      gl2lds16(Bt + (size_t)(gn + r) * Kpad + k0 + ((s ^ (r & 7)) << 3), &Blds[q * 8]);
    }
    __syncthreads();
    #pragma unroll
    for (int ks = 0; ks < 2; ++ks) {
      const int k8 = ks * 4 + kg;
      short8 af[FM];
      #pragma unroll
      for (int m = 0; m < FM; m++) {
        int r = m * 16 + lr;
        af[m] = *(const short8*)(&Alds[(r * 8 + (k8 ^ sx)) * 8]);
      }
      #pragma unroll
      for (int n2 = 0; n2 < FN; n2++) {
        int cc = wid * WCOLS + n2 * 16 + lr;
        short8 bq = *(const short8*)(&Blds[(cc * 8 + (k8 ^ sx)) * 8]);
        #pragma unroll
        for (int m = 0; m < FM; m++)
          acc[m][n2] = __builtin_amdgcn_mfma_f32_16x16x32_bf16(af[m], bq, acc[m][n2], 0, 0, 0);
      }
    }
    __syncthreads();
  }
  #pragma unroll
  for (int m = 0; m < FM; m++) {
    #pragma unroll
    for (int jj = 0; jj < 4; jj++) {
      int grow = gm + m * 16 + kg * 4 + jj;
      if (grow < M) {
        #pragma unroll
        for (int n2 = 0; n2 < FN; n2++) {
          int gcol = gn + wid * WCOLS + n2 * 16 + lr;
          float v = acc[m][n2][jj];
          if constexpr (ADD_BIAS) v += bias[gcol];
          if constexpr (DO_RELU) v = fmaxf(v, 0.f);
          C[(size_t)grow * N + gcol] = f2bf(v);
        }
      }
    }
  }
}

// ---------------- fused dual-graph GCN scatter ----------------
// out = w * act(gcnA(hA)+bA) + (1-w) * act(gcnB(hB)+bB), act = relu or identity.
template<int F, int LDHA, int LDHB, bool DO_RELU, bool OUT_BF16>
__global__ __launch_bounds__(256)
void scatter_fused(const unsigned short* __restrict__ hA, const unsigned short* __restrict__ hB,
                   const int* __restrict__ rpA, const int* __restrict__ csA,
                   const float* __restrict__ cnA, const float* __restrict__ dvA,
                   const float* __restrict__ bA,
                   const int* __restrict__ rpB, const int* __restrict__ csB,
                   const float* __restrict__ cnB, const float* __restrict__ dvB,
                   const float* __restrict__ bB,
                   const float* __restrict__ wptr, void* __restrict__ outp, int n) {
  constexpr int TPN = F / 4;
  const int tid = threadIdx.x;
  const int node = blockIdx.x * (256 / TPN) + tid / TPN;
  const int c4 = (tid % TPN) * 4;
  if (node >= n) return;

  f32x4 accA, accB, t2 = {0.f, 0.f, 0.f, 0.f};
  {
    float d = dvA[node]; float sc = d * d;
    short4v v = *(const short4v*)(hA + (size_t)node * LDHA + c4);
    accA[0] = sc * bf2f((unsigned short)v[0]);
    accA[1] = sc * bf2f((unsigned short)v[1]);
    accA[2] = sc * bf2f((unsigned short)v[2]);
    accA[3] = sc * bf2f((unsigned short)v[3]);
    const int e1 = rpA[node + 1];
    int e = rpA[node];
    for (; e + 2 <= e1; e += 2) {
      int s0 = csA[e], s1 = csA[e + 1];
      float n0 = cnA[e], n1 = cnA[e + 1];
      short4v v0 = *(const short4v*)(hA + (size_t)s0 * LDHA + c4);
      short4v v1 = *(const short4v*)(hA + (size_t)s1 * LDHA + c4);
      accA[0] += n0 * bf2f((unsigned short)v0[0]); t2[0] += n1 * bf2f((unsigned short)v1[0]);
      accA[1] += n0 * bf2f((unsigned short)v0[1]); t2[1] += n1 * bf2f((unsigned short)v1[1]);
      accA[2] += n0 * bf2f((unsigned short)v0[2]); t2[2] += n1 * bf2f((unsigned short)v1[2]);
      accA[3] += n0 * bf2f((unsigned short)v0[3]); t2[3] += n1 * bf2f((unsigned short)v1[3]);
    }
    if (e < e1) {
      int s0 = csA[e]; float n0 = cnA[e];
      short4v v0 = *(const short4v*)(hA + (size_t)s0 * LDHA + c4);
      accA[0] += n0 * bf2f((unsigned short)v0[0]);
      accA[1] += n0 * bf2f((unsigned short)v0[1]);
      accA[2] += n0 * bf2f((unsigned short)v0[2]);
      accA[3] += n0 * bf2f((unsigned short)v0[3]);
    }
    #pragma unroll
    for (int i = 0; i < 4; i++) { accA[i] += t2[i]; t2[i] = 0.f; }
  }
  {
    float d = dvB[node]; float sc = d * d;
    short4v v = *(const short4v*)(hB + (size_t)node * LDHB + c4);
    accB[0] = sc * bf2f((unsigned short)v[0]);
    accB[1] = sc * bf2f((unsigned short)v[1]);
    accB[2] = sc * bf2f((unsigned short)v[2]);
    accB[3] = sc * bf2f((unsigned short)v[3]);
    const int e1 = rpB[node + 1];
    int e = rpB[node];
    for (; e + 2 <= e1; e += 2) {
      int s0 = csB[e], s1 = csB[e + 1];
      float n0 = cnB[e], n1 = cnB[e + 1];
      short4v v0 = *(const short4v*)(hB + (size_t)s0 * LDHB + c4);
      short4v v1 = *(const short4v*)(hB + (size_t)s1 * LDHB + c4);
      accB[0] += n0 * bf2f((unsigned short)v0[0]); t2[0] += n1 * bf2f((unsigned short)v1[0]);
      accB[1] += n0 * bf2f((unsigned short)v0[1]); t2[1] += n1 * bf2f((unsigned short)v1[1]);
      accB[2] += n0 * bf2f((unsigned short)v0[2]); t2[2] += n1 * bf2f((unsigned short)v1[2]);
      accB[3] += n0 * bf2f((unsigned short)v0[3]); t2[3] += n1 * bf2f((unsigned short)v1[3]);
    }
    if (e < e1) {
      int s0 = csB[e]; float n0 = cnB[e];
      short4v v0 = *(const short4v*)(hB + (size_t)s0 * LDHB + c4);
      accB[0] += n0 * bf2f((unsigned short)v0[0]);
      accB[1] += n0 * bf2f((unsigned short)v0[1]);
      accB[2] += n0 * bf2f((unsigned short)v0[2]);
      accB[3] += n0 * bf2f((unsigned short)v0[3]);
    }
    #pragma unroll
    for (int i = 0; i < 4; i++) accB[i] += t2[i];
  }
  f32x4 bvA = *(const f32x4*)(bA + c4);
  f32x4 bvB = *(const f32x4*)(bB + c4);
  float w = *wptr;
  size_t idx = (size_t)node * F + c4;
  f32x4 r;
  #pragma unroll
  for (int i = 0; i < 4; i++) {
    float va = accA[i] + bvA[i];
    float vb = accB[i] + bvB[i];
    if constexpr (DO_RELU) { va = fmaxf(va, 0.f); vb = fmaxf(vb, 0.f); }
    r[i] = w * va + (1.f - w) * vb;
  }
  if constexpr (OUT_BF16) {
    short4v o;
    o[0] = (short)f2bf(r[0]); o[1] = (short)f2bf(r[1]);
    o[2] = (short)f2bf(r[2]); o[3] = (short)f2bf(r[3]);
    *(short4v*)((unsigned short*)outp + idx) = o;
  } else {
    *(f32x4*)((float*)outp + idx) = r;
  }
}

// ---------------- host ----------------
extern "C" void kernel_launch(void* const* d_in, const int* in_sizes, int n_in,
                              void* d_out, int out_size, void* d_ws, size_t ws_size,
                              hipStream_t stream) {
  const float* gene  = (const float*)d_in[0];
  const float* img   = (const float*)d_in[1];
  const int* ei_ge = (const int*)d_in[2];   // integers arrive as int32
  const int* ei_sp = (const int*)d_in[3];
  const float* W_fc1 = (const float*)d_in[4];  const float* b_fc1 = (const float*)d_in[5];
  const float* W_fc2 = (const float*)d_in[6];  const float* b_fc2 = (const float*)d_in[7];
  const float* W_g11 = (const float*)d_in[8];  const float* b_g11 = (const float*)d_in[9];
  const float* W_g12 = (const float*)d_in[10]; const float* b_g12 = (const float*)d_in[11];
  const float* W_g21 = (const float*)d_in[12]; const float* b_g21 = (const float*)d_in[13];
  const float* W_g22 = (const float*)d_in[14]; const float* b_g22 = (const float*)d_in[15];
  const float* w1p   = (const float*)d_in[16];
  const float* w2p   = (const float*)d_in[17];

  const int Nn = 50000;
  const int E_ge = in_sizes[2] / 2;
  const int E_sp = in_sizes[3] / 2;
  const int NT_M = CDIV(Nn, 64);             // 782 M-tiles of 64
  const int PER  = CDIV(NT_M, 8);            // 98
  const int G1   = 8 * PER;                  // 784 (NT_N=1)
  const int G2   = 8 * PER * 2;              // 1568 (NT_N=2)

  char* ws = (char*)d_ws;
  size_t off = 0;
  auto alloc = [&](size_t bytes) -> void* {
    void* p = ws + off;
    off += (bytes + 255) & ~(size_t)255;
    return p;
  };

  unsigned short* Wt1  = (unsigned short*)alloc((size_t)512 * 3008 * 2);
  unsigned short* Wt2  = (unsigned short*)alloc((size_t)512 * 1024 * 2);
  unsigned short* Wt11 = (unsigned short*)alloc((size_t)256 * 512 * 2);
  unsigned short* Wt12 = (unsigned short*)alloc((size_t)256 * 512 * 2);
  unsigned short* WtC  = (unsigned short*)alloc((size_t)128 * 256 * 2);  // [W_g21 | W_g22] rows
  int*   deg_sp  = (int*)alloc((size_t)Nn * 4);
  int*   deg_ge  = (int*)alloc((size_t)Nn * 4);
  float* dinv_sp = (float*)alloc((size_t)Nn * 4);
  float* dinv_ge = (float*)alloc((size_t)Nn * 4);
  int*   rp_sp   = (int*)alloc((size_t)(Nn + 1) * 4);
  int*   rp_ge   = (int*)alloc((size_t)(Nn + 1) * 4);
  int*   cursor  = (int*)alloc((size_t)Nn * 4);
  int*   csrc_sp = (int*)alloc((size_t)E_sp * 4);
  float* cnrm_sp = (float*)alloc((size_t)E_sp * 4);
  int*   csrc_ge = (int*)alloc((size_t)E_ge * 4);
  float* cnrm_ge = (float*)alloc((size_t)E_ge * 4);
  unsigned short* xbuf1 = (unsigned short*)alloc((size_t)Nn * 512 * 2);  // x1 / Xc
  unsigned short* xbuf2 = (unsigned short*)alloc((size_t)Nn * 512 * 2);  // x2
  unsigned short* tmpA  = (unsigned short*)alloc((size_t)Nn * 256 * 2);  // g11 out; later tmp2
  unsigned short* tmpB  = (unsigned short*)alloc((size_t)Nn * 256 * 2);  // g12 out
  unsigned short* Xc    = xbuf1;
  unsigned short* tmp2  = tmpA;
  (void)ws_size; (void)n_in; (void)out_size;

  // 1. weight transposes (bf16, K zero-padded)
  transpose_w<<<dim3(94, 16), 256, 0, stream>>>(W_fc1, Wt1, 3000, 512, 3008);
  transpose_w<<<dim3(32, 16), 256, 0, stream>>>(W_fc2, Wt2, 1024, 512, 1024);
  transpose_w<<<dim3(16, 8),  256, 0, stream>>>(W_g11, Wt11, 512, 256, 512);
  transpose_w<<<dim3(16, 8),  256, 0, stream>>>(W_g12, Wt12, 512, 256, 512);
  transpose_w<<<dim3(8, 2),   256, 0, stream>>>(W_g21, WtC, 256, 64, 256);
  transpose_w<<<dim3(8, 2),   256, 0, stream>>>(W_g22, WtC + (size_t)64 * 256, 256, 64, 256);

  // 2. graph prep
  deg_init<<<CDIV(Nn, 256), 256, 0, stream>>>(deg_sp, deg_ge, Nn);
  deg_hist<<<CDIV(E_sp, 256), 256, 0, stream>>>(ei_sp, E_sp, deg_sp, Nn);
  deg_hist<<<CDIV(E_ge, 256), 256, 0, stream>>>(ei_ge, E_ge, deg_ge, Nn);
  dinv_k<<<CDIV(Nn, 256), 256, 0, stream>>>(deg_sp, dinv_sp, Nn);
  dinv_k<<<CDIV(Nn, 256), 256, 0, stream>>>(deg_ge, dinv_ge, Nn);
  scan_rowptr<<<1, 1024, 0, stream>>>(deg_sp, rp_sp, Nn);
  scan_rowptr<<<1, 1024, 0, stream>>>(deg_ge, rp_ge, Nn);
  zero_i32<<<CDIV(Nn, 256), 256, 0, stream>>>(cursor, Nn);
  csr_fill<<<CDIV(E_sp, 256), 256, 0, stream>>>(ei_sp, E_sp, rp_sp, cursor, dinv_sp, csrc_sp, cnrm_sp, Nn);
  zero_i32<<<CDIV(Nn, 256), 256, 0, stream>>>(cursor, Nn);
  csr_fill<<<CDIV(E_ge, 256), 256, 0, stream>>>(ei_ge, E_ge, rp_ge, cursor, dinv_ge, csrc_ge, cnrm_ge, Nn);

  // 3. FC1 + FC2 fused in one launch (job = bid&1): x1 = relu(gene@W1+b), x2 = relu(img@W2+b)
  gemm_dual<64, 256, 256, 2, 3, true, true><<<2 * G2, 256, 0, stream>>>(
      gene, Wt1, b_fc1, xbuf1, 3000, 3008,
      img,  Wt2, b_fc2, xbuf2, 1024, 1024,
      NT_M, Nn, 512);
  // 4. steps 4+7 fused: tmpA = x1 @ W_g11 ; tmpB = x2 @ W_g12
  gemm_dual<64, 256, 256, 1, 1, false, false><<<2 * G1, 256, 0, stream>>>(
      xbuf1, Wt11, nullptr, tmpA, 512, 512,
      xbuf2, Wt12, nullptr, tmpB, 512, 512,
      NT_M, Nn, 256);
  // 5. Xc = bf16( w1*relu(gcn_sp(tmpA)+b_g11) + (1-w1)*relu(gcn_ge(tmpB)+b_g12) )
  scatter_fused<256, 256, 256, true, true><<<Nn / 4, 256, 0, stream>>>(
      tmpA, tmpB, rp_sp, csrc_sp, cnrm_sp, dinv_sp, b_g11,
      rp_ge, csrc_ge, cnrm_ge, dinv_ge, b_g12, w1p, Xc, Nn);
  // 6. tmp2 = Xc @ [W_g21 | W_g22]  (N=128, one pass; tmp2 aliases tmpA)
  gemm7<64, 128, 256, 1, false, false><<<G1, 256, 0, stream>>>(
      Xc, WtC, nullptr, tmp2, NT_M, Nn, 128, 256, 256);
  // 7. d_out = w2*(gcn_sp(tmp2[:,0:64])+b_g21) + (1-w2)*(gcn_ge(tmp2[:,64:128])+b_g22)
  scatter_fused<64, 128, 128, false, false><<<Nn / 16, 256, 0, stream>>>(
      tmp2, tmp2 + 64, rp_sp, csrc_sp, cnrm_sp, dinv_sp, b_g21,
      rp_ge, csrc_ge, cnrm_ge, dinv_ge, b_g22, w2p, d_out, Nn);
}

// Round 13
// 950.750 us; speedup vs baseline: 1.4003x; 1.0411x over previous
//
#include <hip/hip_runtime.h>
#include <hip/hip_bf16.h>
#include <stdint.h>

typedef __attribute__((ext_vector_type(4))) float f32x4;
typedef __attribute__((ext_vector_type(8))) short short8;
typedef __attribute__((ext_vector_type(4))) short short4v;

#define CDIV(a, b) (((a) + (b) - 1) / (b))

__device__ __forceinline__ unsigned short f2bf(float x) {
  union { float f; unsigned int u; } c; c.f = x;
  unsigned int r = c.u + 0x7FFFu + ((c.u >> 16) & 1u);   // round-to-nearest-even
  return (unsigned short)(r >> 16);
}
__device__ __forceinline__ unsigned short f2bf_hw(float x) {
  __hip_bfloat16 h = __float2bfloat16(x);                // pairs fuse into v_cvt_pk_bf16_f32
  unsigned short u; __builtin_memcpy(&u, &h, 2); return u;
}
__device__ __forceinline__ float bf2f(unsigned short b) {
  union { unsigned int u; float f; } c; c.u = (unsigned int)b << 16; return c.f;
}

// async global->LDS, 16B per lane; LDS dest must be wave-uniform base + lane*16 (linear)
__device__ __forceinline__ void gl2lds16(const void* g, void* lds) {
  __builtin_amdgcn_global_load_lds(
      reinterpret_cast<const __attribute__((address_space(1))) unsigned int*>(
          reinterpret_cast<uintptr_t>(g)),
      reinterpret_cast<__attribute__((address_space(3))) unsigned int*>(
          reinterpret_cast<uintptr_t>(lds)),
      16, 0, 0);
}

// ---------------- weight transpose: W[K][N] f32 -> Wt[N][Kpad] bf16, zero-padded ----------------
__global__ void transpose_w(const float* __restrict__ W, unsigned short* __restrict__ Wt,
                            int K, int N, int Kpad) {
  __shared__ float tile[32][33];
  int kb = blockIdx.x * 32, nb = blockIdx.y * 32;
  int tx = threadIdx.x & 31, ty = threadIdx.x >> 5;  // 256 threads = 32x8
  for (int r = ty; r < 32; r += 8) {
    int k = kb + r, n = nb + tx;
    tile[r][tx] = (k < K && n < N) ? W[(size_t)k * N + n] : 0.f;
  }
  __syncthreads();
  for (int r = ty; r < 32; r += 8) {
    int n = nb + r, k = kb + tx;
    if (n < N && k < Kpad) Wt[(size_t)n * Kpad + k] = f2bf(tile[tx][r]);
  }
}

// ---------------- graph prep ----------------
__global__ void zero_i32(int* __restrict__ p, int n) {
  int i = blockIdx.x * blockDim.x + threadIdx.x;
  if (i < n) p[i] = 0;
}

__global__ void deg_init(int* __restrict__ a, int* __restrict__ b, int n) {
  int i = blockIdx.x * blockDim.x + threadIdx.x;
  if (i < n) { a[i] = 1; b[i] = 1; }   // self-loop
}

__global__ void deg_hist(const int* __restrict__ ei, int E, int* __restrict__ deg, int n) {
  int e = blockIdx.x * blockDim.x + threadIdx.x;
  if (e >= E) return;
  unsigned int d = (unsigned int)ei[(size_t)E + e];
  if (d < (unsigned int)n) atomicAdd(&deg[d], 1);
}

__global__ void dinv_k(const int* __restrict__ deg, float* __restrict__ dinv, int n) {
  int i = blockIdx.x * blockDim.x + threadIdx.x;
  if (i < n) dinv[i] = rsqrtf((float)deg[i]);
}

// exclusive scan of (deg-1) -> row_ptr[0..n], single block of 1024, shfl-based
__global__ void scan_rowptr(const int* __restrict__ deg, int* __restrict__ rp, int n) {
  __shared__ int wsum[16];
  __shared__ int carry_s;
  const int tid = threadIdx.x, lane = tid & 63, w = tid >> 6;
  if (tid == 0) carry_s = 0;
  __syncthreads();
  for (int base = 0; base < n; base += 1024) {
    int i = base + tid;
    int d = (i < n) ? (deg[i] - 1) : 0;
    int v = d;
    #pragma unroll
    for (int off = 1; off < 64; off <<= 1) {
      int t = __shfl_up(v, off, 64);
      if (lane >= off) v += t;
    }
    if (lane == 63) wsum[w] = v;
    __syncthreads();
    int carry = carry_s;
    if (w == 0) {
      int s = (lane < 16) ? wsum[lane] : 0;
      #pragma unroll
      for (int off = 1; off < 16; off <<= 1) {
        int t = __shfl_up(s, off, 64);
        if (lane >= off) s += t;
      }
      if (lane < 16) wsum[lane] = s;
    }
    __syncthreads();
    int woff = (w > 0) ? wsum[w - 1] : 0;
    if (i < n) rp[i] = carry + woff + v - d;
    if (tid == 0) carry_s = carry + wsum[15];
    __syncthreads();
  }
  if (threadIdx.x == 0) rp[n] = carry_s;
}

__global__ void csr_fill(const int* __restrict__ ei, int E,
                         const int* __restrict__ row_ptr, int* __restrict__ cursor,
                         const float* __restrict__ dinv,
                         int* __restrict__ csr_src, float* __restrict__ csr_nrm, int n) {
  int e = blockIdx.x * blockDim.x + threadIdx.x;
  if (e >= E) return;
  unsigned int s = (unsigned int)ei[e];
  unsigned int d = (unsigned int)ei[(size_t)E + e];
  if (s >= (unsigned int)n || d >= (unsigned int)n) return;
  int pos = row_ptr[d] + atomicAdd(&cursor[d], 1);
  csr_src[pos] = (int)s;
  csr_nrm[pos] = dinv[s] * dinv[d];
}

// ---------------- gemm13: m97-exact geometry. BM=BN=128, BK=64, TH=256, 2x2 waves ----------------
// Single-buffered 2-barrier loop. AMODE 1: A bf16 via gl2lds (32 KB LDS, ~5 blocks/CU).
// AMODE 3: A f32 RAW via gl2lds, bf16 cvt at fragment read (48 KB LDS, 3 blocks/CU);
// K-tail reg-staged zero-masked (K%4==0). NT_N sibling N-tiles XCD-grouped (A L2-hot).
template<int NT_N, int AMODE, bool ADD_BIAS, bool DO_RELU>
__global__ __launch_bounds__(256, 2)
void gemm13(const void* __restrict__ Av, const unsigned short* __restrict__ Bt,
            const float* __restrict__ bias, unsigned short* __restrict__ C,
            int NT_M, int M, int N, int K, int Kpad) {
  constexpr int BM = 128, BN = 128, BK = 64, TH = 256;
  constexpr int FM = 4, FN = 4;
  constexpr int BIT  = (BN * 8) / TH;    // 4
  constexpr int AIT1 = (BM * 8) / TH;    // 4
  constexpr int AIT3 = (BM * 16) / TH;   // 8
  constexpr int LOGN = (NT_N == 4) ? 2 : (NT_N == 2 ? 1 : 0);

  const int bid = blockIdx.x;
  const int xcd = bid & 7, j = bid >> 3;
  const int per = (NT_M + 7) >> 3;
  const int mt = xcd * per + (j >> LOGN);
  const int nt = j & (NT_N - 1);
  if (mt >= NT_M) return;
  const int gm = mt * BM, gn = nt * BN;

  constexpr int ABYTES = (AMODE == 3) ? BM * BK * 4 : BM * BK * 2;
  __shared__ __align__(16) char AldsRaw[ABYTES];
  __shared__ __align__(16) unsigned short Blds[BN * BK];

  const int tid = threadIdx.x;
  const int wid = tid >> 6, lane = tid & 63;
  const int wm = wid >> 1, wn = wid & 1;     // 2x2 waves, 64x64 each
  const int kg = lane >> 4, lr = lane & 15;
  const int sx = lr & 7;

  f32x4 acc[FM][FN] = {};

  const int nkt = Kpad / BK;
  for (int kt = 0; kt < nkt; ++kt) {
    const int k0 = kt * BK;
    // ---- stage A ----
    if constexpr (AMODE == 1) {
      const unsigned short* A = (const unsigned short*)Av;
      unsigned short* Alds = (unsigned short*)AldsRaw;
      #pragma unroll
      for (int it = 0; it < AIT1; ++it) {
        int q = it * TH + tid;
        int r = q >> 3, s = q & 7;
        int grow = gm + r; if (grow > M - 1) grow = M - 1;
        gl2lds16(A + (size_t)grow * K + k0 + ((s ^ (r & 7)) << 3), &Alds[q * 8]);
      }
    } else {  // AMODE 3: raw f32, 16 slots/row, swizzled source
      const float* A = (const float*)Av;
      float* Af = (float*)AldsRaw;
      if (k0 + BK <= K) {
        #pragma unroll
        for (int it = 0; it < AIT3; ++it) {
          int q = it * TH + tid;
          int r = q >> 4, s = q & 15;
          int grow = gm + r; if (grow > M - 1) grow = M - 1;
          gl2lds16(A + (size_t)grow * K + k0 + ((s ^ (r & 15)) << 2), &Af[q * 4]);
        }
      } else {  // tail (K%4==0): reg-staged, zero-masked
        #pragma unroll
        for (int it = 0; it < AIT3; ++it) {
          int q = it * TH + tid;
          int r = q >> 4, s = q & 15;
          int grow = gm + r; if (grow > M - 1) grow = M - 1;
          int kbase = k0 + ((s ^ (r & 15)) << 2);
          f32x4 v = {0.f, 0.f, 0.f, 0.f};
          if (kbase + 4 <= K) v = *(const f32x4*)(A + (size_t)grow * K + kbase);
          *(f32x4*)(&Af[q * 4]) = v;
        }
      }
    }
    // ---- stage B via gl2lds (linear dest, inverse-swizzled source) ----
    #pragma unroll
    for (int it = 0; it < BIT; ++it) {
      int q = it * TH + tid;
      int r = q >> 3, s = q & 7;
      gl2lds16(Bt + (size_t)(gn + r) * Kpad + k0 + ((s ^ (r & 7)) << 3), &Blds[q * 8]);
    }
    __syncthreads();
    // ---- fragments + MFMA (2 K-slices of 32) ----
    #pragma unroll
    for (int ks = 0; ks < 2; ++ks) {
      const int k8 = ks * 4 + kg;
      short8 af[FM];
      #pragma unroll
      for (int m = 0; m < FM; m++) {
        int r = wm * 64 + m * 16 + lr;     // r&15 == lr
        if constexpr (AMODE == 1) {
          const unsigned short* Alds = (const unsigned short*)AldsRaw;
          af[m] = *(const short8*)(&Alds[(r * 8 + (k8 ^ sx)) * 8]);
        } else {
          const float* Af = (const float*)AldsRaw;
          int s0 = (2 * k8) ^ lr, s1 = (2 * k8 + 1) ^ lr;
          f32x4 lo = *(const f32x4*)(Af + r * 64 + s0 * 4);
          f32x4 hi = *(const f32x4*)(Af + r * 64 + s1 * 4);
          #pragma unroll
          for (int i = 0; i < 4; i++) {
            af[m][i]     = (short)f2bf_hw(lo[i]);
            af[m][i + 4] = (short)f2bf_hw(hi[i]);
          }
        }
      }
      #pragma unroll
      for (int n2 = 0; n2 < FN; n2++) {
        int cc = wn * 64 + n2 * 16 + lr;
        short8 bq = *(const short8*)(&Blds[(cc * 8 + (k8 ^ sx)) * 8]);
        #pragma unroll
        for (int m = 0; m < FM; m++)
          acc[m][n2] = __builtin_amdgcn_mfma_f32_16x16x32_bf16(af[m], bq, acc[m][n2], 0, 0, 0);
      }
    }
    __syncthreads();
  }
  // ---- epilogue: C/D layout col=lane&15, row=(lane>>4)*4+reg ----
  #pragma unroll
  for (int m = 0; m < FM; m++) {
    #pragma unroll
    for (int jj = 0; jj < 4; jj++) {
      int grow = gm + wm * 64 + m * 16 + kg * 4 + jj;
      if (grow < M) {
        #pragma unroll
        for (int n2 = 0; n2 < FN; n2++) {
          int gcol = gn + wn * 64 + n2 * 16 + lr;
          float v = acc[m][n2][jj];
          if constexpr (ADD_BIAS) v += bias[gcol];
          if constexpr (DO_RELU) v = fmaxf(v, 0.f);
          C[(size_t)grow * N + gcol] = f2bf(v);
        }
      }
    }
  }
}

// ---------------- fused dual-graph GCN scatter ----------------
// out = w * act(gcnA(hA)+bA) + (1-w) * act(gcnB(hB)+bB), act = relu or identity.
template<int F, int LDHA, int LDHB, bool DO_RELU, bool OUT_BF16>
__global__ __launch_bounds__(256)
void scatter_fused(const unsigned short* __restrict__ hA, const unsigned short* __restrict__ hB,
                   const int* __restrict__ rpA, const int* __restrict__ csA,
                   const float* __restrict__ cnA, const float* __restrict__ dvA,
                   const float* __restrict__ bA,
                   const int* __restrict__ rpB, const int* __restrict__ csB,
                   const float* __restrict__ cnB, const float* __restrict__ dvB,
                   const float* __restrict__ bB,
                   const float* __restrict__ wptr, void* __restrict__ outp, int n) {
  constexpr int TPN = F / 4;
  const int tid = threadIdx.x;
  const int node = blockIdx.x * (256 / TPN) + tid / TPN;
  const int c4 = (tid % TPN) * 4;
  if (node >= n) return;

  f32x4 accA, accB, t2 = {0.f, 0.f, 0.f, 0.f};
  {
    float d = dvA[node]; float sc = d * d;
    short4v v = *(const short4v*)(hA + (size_t)node * LDHA + c4);
    accA[0] = sc * bf2f((unsigned short)v[0]);
    accA[1] = sc * bf2f((unsigned short)v[1]);
    accA[2] = sc * bf2f((unsigned short)v[2]);
    accA[3] = sc * bf2f((unsigned short)v[3]);
    const int e1 = rpA[node + 1];
    int e = rpA[node];
    for (; e + 2 <= e1; e += 2) {
      int s0 = csA[e], s1 = csA[e + 1];
      float n0 = cnA[e], n1 = cnA[e + 1];
      short4v v0 = *(const short4v*)(hA + (size_t)s0 * LDHA + c4);
      short4v v1 = *(const short4v*)(hA + (size_t)s1 * LDHA + c4);
      accA[0] += n0 * bf2f((unsigned short)v0[0]); t2[0] += n1 * bf2f((unsigned short)v1[0]);
      accA[1] += n0 * bf2f((unsigned short)v0[1]); t2[1] += n1 * bf2f((unsigned short)v1[1]);
      accA[2] += n0 * bf2f((unsigned short)v0[2]); t2[2] += n1 * bf2f((unsigned short)v1[2]);
      accA[3] += n0 * bf2f((unsigned short)v0[3]); t2[3] += n1 * bf2f((unsigned short)v1[3]);
    }
    if (e < e1) {
      int s0 = csA[e]; float n0 = cnA[e];
      short4v v0 = *(const short4v*)(hA + (size_t)s0 * LDHA + c4);
      accA[0] += n0 * bf2f((unsigned short)v0[0]);
      accA[1] += n0 * bf2f((unsigned short)v0[1]);
      accA[2] += n0 * bf2f((unsigned short)v0[2]);
      accA[3] += n0 * bf2f((unsigned short)v0[3]);
    }
    #pragma unroll
    for (int i = 0; i < 4; i++) { accA[i] += t2[i]; t2[i] = 0.f; }
  }
  {
    float d = dvB[node]; float sc = d * d;
    short4v v = *(const short4v*)(hB + (size_t)node * LDHB + c4);
    accB[0] = sc * bf2f((unsigned short)v[0]);
    accB[1] = sc * bf2f((unsigned short)v[1]);
    accB[2] = sc * bf2f((unsigned short)v[2]);
    accB[3] = sc * bf2f((unsigned short)v[3]);
    const int e1 = rpB[node + 1];
    int e = rpB[node];
    for (; e + 2 <= e1; e += 2) {
      int s0 = csB[e], s1 = csB[e + 1];
      float n0 = cnB[e], n1 = cnB[e + 1];
      short4v v0 = *(const short4v*)(hB + (size_t)s0 * LDHB + c4);
      short4v v1 = *(const short4v*)(hB + (size_t)s1 * LDHB + c4);
      accB[0] += n0 * bf2f((unsigned short)v0[0]); t2[0] += n1 * bf2f((unsigned short)v1[0]);
      accB[1] += n0 * bf2f((unsigned short)v0[1]); t2[1] += n1 * bf2f((unsigned short)v1[1]);
      accB[2] += n0 * bf2f((unsigned short)v0[2]); t2[2] += n1 * bf2f((unsigned short)v1[2]);
      accB[3] += n0 * bf2f((unsigned short)v0[3]); t2[3] += n1 * bf2f((unsigned short)v1[3]);
    }
    if (e < e1) {
      int s0 = csB[e]; float n0 = cnB[e];
      short4v v0 = *(const short4v*)(hB + (size_t)s0 * LDHB + c4);
      accB[0] += n0 * bf2f((unsigned short)v0[0]);
      accB[1] += n0 * bf2f((unsigned short)v0[1]);
      accB[2] += n0 * bf2f((unsigned short)v0[2]);
      accB[3] += n0 * bf2f((unsigned short)v0[3]);
    }
    #pragma unroll
    for (int i = 0; i < 4; i++) accB[i] += t2[i];
  }
  f32x4 bvA = *(const f32x4*)(bA + c4);
  f32x4 bvB = *(const f32x4*)(bB + c4);
  float w = *wptr;
  size_t idx = (size_t)node * F + c4;
  f32x4 r;
  #pragma unroll
  for (int i = 0; i < 4; i++) {
    float va = accA[i] + bvA[i];
    float vb = accB[i] + bvB[i];
    if constexpr (DO_RELU) { va = fmaxf(va, 0.f); vb = fmaxf(vb, 0.f); }
    r[i] = w * va + (1.f - w) * vb;
  }
  if constexpr (OUT_BF16) {
    short4v o;
    o[0] = (short)f2bf(r[0]); o[1] = (short)f2bf(r[1]);
    o[2] = (short)f2bf(r[2]); o[3] = (short)f2bf(r[3]);
    *(short4v*)((unsigned short*)outp + idx) = o;
  } else {
    *(f32x4*)((float*)outp + idx) = r;
  }
}

// ---------------- host ----------------
extern "C" void kernel_launch(void* const* d_in, const int* in_sizes, int n_in,
                              void* d_out, int out_size, void* d_ws, size_t ws_size,
                              hipStream_t stream) {
  const float* gene  = (const float*)d_in[0];
  const float* img   = (const float*)d_in[1];
  const int* ei_ge = (const int*)d_in[2];   // integers arrive as int32
  const int* ei_sp = (const int*)d_in[3];
  const float* W_fc1 = (const float*)d_in[4];  const float* b_fc1 = (const float*)d_in[5];
  const float* W_fc2 = (const float*)d_in[6];  const float* b_fc2 = (const float*)d_in[7];
  const float* W_g11 = (const float*)d_in[8];  const float* b_g11 = (const float*)d_in[9];
  const float* W_g12 = (const float*)d_in[10]; const float* b_g12 = (const float*)d_in[11];
  const float* W_g21 = (const float*)d_in[12]; const float* b_g21 = (const float*)d_in[13];
  const float* W_g22 = (const float*)d_in[14]; const float* b_g22 = (const float*)d_in[15];
  const float* w1p   = (const float*)d_in[16];
  const float* w2p   = (const float*)d_in[17];

  const int Nn = 50000;
  const int E_ge = in_sizes[2] / 2;
  const int E_sp = in_sizes[3] / 2;
  const int NT_M = CDIV(Nn, 128);            // 391 M-tiles of 128
  const int PER  = CDIV(NT_M, 8);            // 49
  const int G1   = 8 * PER;                  // 392 (NT_N=1)
  const int G2   = 8 * PER * 2;              // 784 (NT_N=2)
  const int G4   = 8 * PER * 4;              // 1568 (NT_N=4)

  char* ws = (char*)d_ws;
  size_t off = 0;
  auto alloc = [&](size_t bytes) -> void* {
    void* p = ws + off;
    off += (bytes + 255) & ~(size_t)255;
    return p;
  };

  unsigned short* Wt1  = (unsigned short*)alloc((size_t)512 * 3008 * 2);
  unsigned short* Wt2  = (unsigned short*)alloc((size_t)512 * 1024 * 2);
  unsigned short* Wt11 = (unsigned short*)alloc((size_t)256 * 512 * 2);
  unsigned short* Wt12 = (unsigned short*)alloc((size_t)256 * 512 * 2);
  unsigned short* WtC  = (unsigned short*)alloc((size_t)128 * 256 * 2);  // [W_g21 | W_g22] rows
  int*   deg_sp  = (int*)alloc((size_t)Nn * 4);
  int*   deg_ge  = (int*)alloc((size_t)Nn * 4);
  float* dinv_sp = (float*)alloc((size_t)Nn * 4);
  float* dinv_ge = (float*)alloc((size_t)Nn * 4);
  int*   rp_sp   = (int*)alloc((size_t)(Nn + 1) * 4);
  int*   rp_ge   = (int*)alloc((size_t)(Nn + 1) * 4);
  int*   cursor  = (int*)alloc((size_t)Nn * 4);
  int*   csrc_sp = (int*)alloc((size_t)E_sp * 4);
  float* cnrm_sp = (float*)alloc((size_t)E_sp * 4);
  int*   csrc_ge = (int*)alloc((size_t)E_ge * 4);
  float* cnrm_ge = (float*)alloc((size_t)E_ge * 4);
  unsigned short* xbuf1 = (unsigned short*)alloc((size_t)Nn * 512 * 2);  // x1 / Xc
  unsigned short* xbuf2 = (unsigned short*)alloc((size_t)Nn * 512 * 2);  // x2
  unsigned short* tmpA  = (unsigned short*)alloc((size_t)Nn * 256 * 2);  // g11 out; later tmp2
  unsigned short* tmpB  = (unsigned short*)alloc((size_t)Nn * 256 * 2);  // g12 out
  unsigned short* Xc    = xbuf1;
  unsigned short* tmp2  = tmpA;
  (void)ws_size; (void)n_in; (void)out_size;

  // 1. weight transposes (bf16, K zero-padded)
  transpose_w<<<dim3(94, 16), 256, 0, stream>>>(W_fc1, Wt1, 3000, 512, 3008);
  transpose_w<<<dim3(32, 16), 256, 0, stream>>>(W_fc2, Wt2, 1024, 512, 1024);
  transpose_w<<<dim3(16, 8),  256, 0, stream>>>(W_g11, Wt11, 512, 256, 512);
  transpose_w<<<dim3(16, 8),  256, 0, stream>>>(W_g12, Wt12, 512, 256, 512);
  transpose_w<<<dim3(8, 2),   256, 0, stream>>>(W_g21, WtC, 256, 64, 256);
  transpose_w<<<dim3(8, 2),   256, 0, stream>>>(W_g22, WtC + (size_t)64 * 256, 256, 64, 256);

  // 2. graph prep
  deg_init<<<CDIV(Nn, 256), 256, 0, stream>>>(deg_sp, deg_ge, Nn);
  deg_hist<<<CDIV(E_sp, 256), 256, 0, stream>>>(ei_sp, E_sp, deg_sp, Nn);
  deg_hist<<<CDIV(E_ge, 256), 256, 0, stream>>>(ei_ge, E_ge, deg_ge, Nn);
  dinv_k<<<CDIV(Nn, 256), 256, 0, stream>>>(deg_sp, dinv_sp, Nn);
  dinv_k<<<CDIV(Nn, 256), 256, 0, stream>>>(deg_ge, dinv_ge, Nn);
  scan_rowptr<<<1, 1024, 0, stream>>>(deg_sp, rp_sp, Nn);
  scan_rowptr<<<1, 1024, 0, stream>>>(deg_ge, rp_ge, Nn);
  zero_i32<<<CDIV(Nn, 256), 256, 0, stream>>>(cursor, Nn);
  csr_fill<<<CDIV(E_sp, 256), 256, 0, stream>>>(ei_sp, E_sp, rp_sp, cursor, dinv_sp, csrc_sp, cnrm_sp, Nn);
  zero_i32<<<CDIV(Nn, 256), 256, 0, stream>>>(cursor, Nn);
  csr_fill<<<CDIV(E_ge, 256), 256, 0, stream>>>(ei_ge, E_ge, rp_ge, cursor, dinv_ge, csrc_ge, cnrm_ge, Nn);

  // 3. x1 = relu(gene @ W_fc1 + b) -> bf16   (m97 128x128, AMODE3, NT_N=4)
  gemm13<4, 3, true, true><<<G4, 256, 0, stream>>>(
      gene, Wt1, b_fc1, xbuf1, NT_M, Nn, 512, 3000, 3008);
  // 4. x2 = relu(img @ W_fc2 + b) -> bf16
  gemm13<4, 3, true, true><<<G4, 256, 0, stream>>>(
      img, Wt2, b_fc2, xbuf2, NT_M, Nn, 512, 1024, 1024);
  // 5. tmpA = x1 @ W_g11  (m97 128x128, AMODE1, NT_N=2)
  gemm13<2, 1, false, false><<<G2, 256, 0, stream>>>(
      xbuf1, Wt11, nullptr, tmpA, NT_M, Nn, 256, 512, 512);
  // 6. tmpB = x2 @ W_g12
  gemm13<2, 1, false, false><<<G2, 256, 0, stream>>>(
      xbuf2, Wt12, nullptr, tmpB, NT_M, Nn, 256, 512, 512);
  // 7. Xc = bf16( w1*relu(gcn_sp(tmpA)+b_g11) + (1-w1)*relu(gcn_ge(tmpB)+b_g12) )
  scatter_fused<256, 256, 256, true, true><<<Nn / 4, 256, 0, stream>>>(
      tmpA, tmpB, rp_sp, csrc_sp, cnrm_sp, dinv_sp, b_g11,
      rp_ge, csrc_ge, cnrm_ge, dinv_ge, b_g12, w1p, Xc, Nn);
  // 8. tmp2 = Xc @ [W_g21 | W_g22]  (N=128, one pass; tmp2 aliases tmpA)
  gemm13<1, 1, false, false><<<G1, 256, 0, stream>>>(
      Xc, WtC, nullptr, tmp2, NT_M, Nn, 128, 256, 256);
  // 9. d_out = w2*(gcn_sp(tmp2[:,0:64])+b_g21) + (1-w2)*(gcn_ge(tmp2[:,64:128])+b_g22)
  scatter_fused<64, 128, 128, false, false><<<Nn / 16, 256, 0, stream>>>(
      tmp2, tmp2 + 64, rp_sp, csrc_sp, cnrm_sp, dinv_sp, b_g21,
      rp_ge, csrc_ge, cnrm_ge, dinv_ge, b_g22, w2p, d_out, Nn);
}

// Round 14
// 836.127 us; speedup vs baseline: 1.5923x; 1.1371x over previous
//
#include <hip/hip_runtime.h>
#include <hip/hip_bf16.h>
#include <stdint.h>

typedef __attribute__((ext_vector_type(4))) float f32x4;
typedef __attribute__((ext_vector_type(8))) short short8;
typedef __attribute__((ext_vector_type(4))) short short4v;

#define CDIV(a, b) (((a) + (b) - 1) / (b))

__device__ __forceinline__ unsigned short f2bf(float x) {
  union { float f; unsigned int u; } c; c.f = x;
  unsigned int r = c.u + 0x7FFFu + ((c.u >> 16) & 1u);   // round-to-nearest-even
  return (unsigned short)(r >> 16);
}
__device__ __forceinline__ unsigned short f2bf_hw(float x) {
  __hip_bfloat16 h = __float2bfloat16(x);                // pairs fuse into v_cvt_pk_bf16_f32
  unsigned short u; __builtin_memcpy(&u, &h, 2); return u;
}
__device__ __forceinline__ float bf2f(unsigned short b) {
  union { unsigned int u; float f; } c; c.u = (unsigned int)b << 16; return c.f;
}

// async global->LDS, 16B per lane; LDS dest must be wave-uniform base + lane*16 (linear)
__device__ __forceinline__ void gl2lds16(const void* g, void* lds) {
  __builtin_amdgcn_global_load_lds(
      reinterpret_cast<const __attribute__((address_space(1))) unsigned int*>(
          reinterpret_cast<uintptr_t>(g)),
      reinterpret_cast<__attribute__((address_space(3))) unsigned int*>(
          reinterpret_cast<uintptr_t>(lds)),
      16, 0, 0);
}

// ---------------- weight transpose: W[K][N] f32 -> Wt[N][Kpad] bf16, zero-padded ----------------
__global__ void transpose_w(const float* __restrict__ W, unsigned short* __restrict__ Wt,
                            int K, int N, int Kpad) {
  __shared__ float tile[32][33];
  int kb = blockIdx.x * 32, nb = blockIdx.y * 32;
  int tx = threadIdx.x & 31, ty = threadIdx.x >> 5;  // 256 threads = 32x8
  for (int r = ty; r < 32; r += 8) {
    int k = kb + r, n = nb + tx;
    tile[r][tx] = (k < K && n < N) ? W[(size_t)k * N + n] : 0.f;
  }
  __syncthreads();
  for (int r = ty; r < 32; r += 8) {
    int n = nb + r, k = kb + tx;
    if (n < N && k < Kpad) Wt[(size_t)n * Kpad + k] = f2bf(tile[tx][r]);
  }
}

// ---------------- graph prep (consolidated: both graphs per launch) ----------------
__global__ void prep_init(int* __restrict__ dA, int* __restrict__ dB,
                          int* __restrict__ cA, int* __restrict__ cB, int n) {
  int i = blockIdx.x * blockDim.x + threadIdx.x;
  if (i < n) { dA[i] = 1; dB[i] = 1; cA[i] = 0; cB[i] = 0; }   // deg=1 (self-loop), cursor=0
}

__global__ void deg_hist_both(const int* __restrict__ eiA, int EA, int* __restrict__ degA,
                              const int* __restrict__ eiB, int EB, int* __restrict__ degB, int n) {
  int e = blockIdx.x * blockDim.x + threadIdx.x;
  if (e < EA) {
    unsigned int d = (unsigned int)eiA[(size_t)EA + e];
    if (d < (unsigned int)n) atomicAdd(&degA[d], 1);
  } else if (e < EA + EB) {
    int e2 = e - EA;
    unsigned int d = (unsigned int)eiB[(size_t)EB + e2];
    if (d < (unsigned int)n) atomicAdd(&degB[d], 1);
  }
}

__global__ void dinv_both(const int* __restrict__ dA, float* __restrict__ vA,
                          const int* __restrict__ dB, float* __restrict__ vB, int n) {
  int i = blockIdx.x * blockDim.x + threadIdx.x;
  if (i < n) { vA[i] = rsqrtf((float)dA[i]); vB[i] = rsqrtf((float)dB[i]); }
}

// exclusive scan of (deg-1) -> row_ptr[0..n]; blockIdx.x selects graph
__global__ void scan_rowptr_dual(const int* __restrict__ degA, int* __restrict__ rpA,
                                 const int* __restrict__ degB, int* __restrict__ rpB, int n) {
  const int* deg = (blockIdx.x == 0) ? degA : degB;
  int* rp = (blockIdx.x == 0) ? rpA : rpB;
  __shared__ int wsum[16];
  __shared__ int carry_s;
  const int tid = threadIdx.x, lane = tid & 63, w = tid >> 6;
  if (tid == 0) carry_s = 0;
  __syncthreads();
  for (int base = 0; base < n; base += 1024) {
    int i = base + tid;
    int d = (i < n) ? (deg[i] - 1) : 0;
    int v = d;
    #pragma unroll
    for (int off = 1; off < 64; off <<= 1) {
      int t = __shfl_up(v, off, 64);
      if (lane >= off) v += t;
    }
    if (lane == 63) wsum[w] = v;
    __syncthreads();
    int carry = carry_s;
    if (w == 0) {
      int s = (lane < 16) ? wsum[lane] : 0;
      #pragma unroll
      for (int off = 1; off < 16; off <<= 1) {
        int t = __shfl_up(s, off, 64);
        if (lane >= off) s += t;
      }
      if (lane < 16) wsum[lane] = s;
    }
    __syncthreads();
    int woff = (w > 0) ? wsum[w - 1] : 0;
    if (i < n) rp[i] = carry + woff + v - d;
    if (tid == 0) carry_s = carry + wsum[15];
    __syncthreads();
  }
  if (threadIdx.x == 0) rp[n] = carry_s;
}

__global__ void csr_fill_both(const int* __restrict__ eiA, int EA, const int* __restrict__ rpA,
                              int* __restrict__ curA, const float* __restrict__ dvA,
                              int* __restrict__ csA, float* __restrict__ cnA,
                              const int* __restrict__ eiB, int EB, const int* __restrict__ rpB,
                              int* __restrict__ curB, const float* __restrict__ dvB,
                              int* __restrict__ csB, float* __restrict__ cnB, int n) {
  int e = blockIdx.x * blockDim.x + threadIdx.x;
  if (e < EA) {
    unsigned int s = (unsigned int)eiA[e];
    unsigned int d = (unsigned int)eiA[(size_t)EA + e];
    if (s < (unsigned int)n && d < (unsigned int)n) {
      int pos = rpA[d] + atomicAdd(&curA[d], 1);
      csA[pos] = (int)s;
      cnA[pos] = dvA[s] * dvA[d];
    }
  } else if (e < EA + EB) {
    int e2 = e - EA;
    unsigned int s = (unsigned int)eiB[e2];
    unsigned int d = (unsigned int)eiB[(size_t)EB + e2];
    if (s < (unsigned int)n && d < (unsigned int)n) {
      int pos = rpB[d] + atomicAdd(&curB[d], 1);
      csB[pos] = (int)s;
      cnB[pos] = dvB[s] * dvB[d];
    }
  }
}

// ---------------- gemm7: r8-proven GEMM. BM=64, BK=64, single-buffered 2-barrier loop ----------------
// AMODE 1: A bf16 via gl2lds. AMODE 3: A f32 RAW via gl2lds (16-slot XOR swizzle),
// bf16 cvt at fragment read; K-tail reg-staged zero-masked (K%4==0).
// NT_N>1: XCD-grouped swizzle puts one M-tile's N-tiles on one XCD (A L2-hot).
template<int BM, int BN, int TH, int NT_N, int AMODE, bool ADD_BIAS, bool DO_RELU>
__global__ __launch_bounds__(TH, 2)
void gemm7(const void* __restrict__ Av, const unsigned short* __restrict__ Bt,
           const float* __restrict__ bias, unsigned short* __restrict__ C,
           int NT_M, int M, int N, int K, int Kpad) {
  constexpr int BK = 64;
  constexpr int WN = TH / 64;
  constexpr int WCOLS = BN / WN;
  constexpr int FM = BM / 16, FN = WCOLS / 16;
  constexpr int BIT  = (BN * 8) / TH;
  constexpr int AIT1 = (BM * 8) / TH;
  constexpr int AIT3 = (BM * 16) / TH;
  constexpr int LOGN = (NT_N == 4) ? 2 : (NT_N == 2 ? 1 : 0);

  const int bid = blockIdx.x;
  const int xcd = bid & 7, j = bid >> 3;
  const int per = (NT_M + 7) >> 3;
  const int mt = xcd * per + (j >> LOGN);
  const int nt = j & (NT_N - 1);
  if (mt >= NT_M) return;
  const int gm = mt * BM, gn = nt * BN;

  constexpr int ABYTES = (AMODE == 3) ? BM * BK * 4 : BM * BK * 2;
  __shared__ __align__(16) char AldsRaw[ABYTES];
  __shared__ __align__(16) unsigned short Blds[BN * BK];

  const int tid = threadIdx.x;
  const int wid = tid >> 6, lane = tid & 63;
  const int kg = lane >> 4, lr = lane & 15;
  const int sx = lr & 7;

  f32x4 acc[FM][FN] = {};

  const int nkt = Kpad / BK;
  for (int kt = 0; kt < nkt; ++kt) {
    const int k0 = kt * BK;
    // ---- stage A ----
    if constexpr (AMODE == 1) {
      const unsigned short* A = (const unsigned short*)Av;
      unsigned short* Alds = (unsigned short*)AldsRaw;
      #pragma unroll
      for (int it = 0; it < AIT1; ++it) {
        int q = it * TH + tid;
        int r = q >> 3, s = q & 7;
        int grow = gm + r; if (grow > M - 1) grow = M - 1;
        gl2lds16(A + (size_t)grow * K + k0 + ((s ^ (r & 7)) << 3), &Alds[q * 8]);
      }
    } else {  // AMODE 3: raw f32, 16 slots/row, swizzled source
      const float* A = (const float*)Av;
      float* Af = (float*)AldsRaw;
      if (k0 + BK <= K) {
        #pragma unroll
        for (int it = 0; it < AIT3; ++it) {
          int q = it * TH + tid;
          int r = q >> 4, s = q & 15;
          int grow = gm + r; if (grow > M - 1) grow = M - 1;
          gl2lds16(A + (size_t)grow * K + k0 + ((s ^ (r & 15)) << 2), &Af[q * 4]);
        }
      } else {  // tail (K%4==0): reg-staged, zero-masked
        #pragma unroll
        for (int it = 0; it < AIT3; ++it) {
          int q = it * TH + tid;
          int r = q >> 4, s = q & 15;
          int grow = gm + r; if (grow > M - 1) grow = M - 1;
          int kbase = k0 + ((s ^ (r & 15)) << 2);
          f32x4 v = {0.f, 0.f, 0.f, 0.f};
          if (kbase + 4 <= K) v = *(const f32x4*)(A + (size_t)grow * K + kbase);
          *(f32x4*)(&Af[q * 4]) = v;
        }
      }
    }
    // ---- stage B via gl2lds (linear dest, inverse-swizzled source) ----
    #pragma unroll
    for (int it = 0; it < BIT; ++it) {
      int q = it * TH + tid;
      int r = q >> 3, s = q & 7;
      gl2lds16(Bt + (size_t)(gn + r) * Kpad + k0 + ((s ^ (r & 7)) << 3), &Blds[q * 8]);
    }
    __syncthreads();
    // ---- fragments + MFMA (2 K-slices of 32) ----
    #pragma unroll
    for (int ks = 0; ks < 2; ++ks) {
      const int k8 = ks * 4 + kg;
      short8 af[FM];
      #pragma unroll
      for (int m = 0; m < FM; m++) {
        int r = m * 16 + lr;                 // r & 15 == lr
        if constexpr (AMODE == 1) {
          const unsigned short* Alds = (const unsigned short*)AldsRaw;
          af[m] = *(const short8*)(&Alds[(r * 8 + (k8 ^ sx)) * 8]);
        } else {
          const float* Af = (const float*)AldsRaw;
          int s0 = (2 * k8) ^ lr, s1 = (2 * k8 + 1) ^ lr;
          f32x4 lo = *(const f32x4*)(Af + r * 64 + s0 * 4);
          f32x4 hi = *(const f32x4*)(Af + r * 64 + s1 * 4);
          #pragma unroll
          for (int i = 0; i < 4; i++) {
            af[m][i]     = (short)f2bf_hw(lo[i]);
            af[m][i + 4] = (short)f2bf_hw(hi[i]);
          }
        }
      }
      #pragma unroll
      for (int n2 = 0; n2 < FN; n2++) {
        int cc = wid * WCOLS + n2 * 16 + lr;
        short8 bq = *(const short8*)(&Blds[(cc * 8 + (k8 ^ sx)) * 8]);
        #pragma unroll
        for (int m = 0; m < FM; m++)
          acc[m][n2] = __builtin_amdgcn_mfma_f32_16x16x32_bf16(af[m], bq, acc[m][n2], 0, 0, 0);
      }
    }
    __syncthreads();
  }
  // ---- epilogue: C/D layout col=lane&15, row=(lane>>4)*4+reg ----
  #pragma unroll
  for (int m = 0; m < FM; m++) {
    #pragma unroll
    for (int jj = 0; jj < 4; jj++) {
      int grow = gm + m * 16 + kg * 4 + jj;
      if (grow < M) {
        #pragma unroll
        for (int n2 = 0; n2 < FN; n2++) {
          int gcol = gn + wid * WCOLS + n2 * 16 + lr;
          float v = acc[m][n2][jj];
          if constexpr (ADD_BIAS) v += bias[gcol];
          if constexpr (DO_RELU) v = fmaxf(v, 0.f);
          C[(size_t)grow * N + gcol] = f2bf(v);
        }
      }
    }
  }
}

// ---------------- fused dual-graph GCN scatter ----------------
// out = w * act(gcnA(hA)+bA) + (1-w) * act(gcnB(hB)+bB), act = relu or identity.
// Thread owns 4 cols of one node; both edge loops 2-way unrolled for MLP.
template<int F, int LDHA, int LDHB, bool DO_RELU, bool OUT_BF16>
__global__ __launch_bounds__(256)
void scatter_fused(const unsigned short* __restrict__ hA, const unsigned short* __restrict__ hB,
                   const int* __restrict__ rpA, const int* __restrict__ csA,
                   const float* __restrict__ cnA, const float* __restrict__ dvA,
                   const float* __restrict__ bA,
                   const int* __restrict__ rpB, const int* __restrict__ csB,
                   const float* __restrict__ cnB, const float* __restrict__ dvB,
                   const float* __restrict__ bB,
                   const float* __restrict__ wptr, void* __restrict__ outp, int n) {
  constexpr int TPN = F / 4;
  const int tid = threadIdx.x;
  const int node = blockIdx.x * (256 / TPN) + tid / TPN;
  const int c4 = (tid % TPN) * 4;
  if (node >= n) return;

  f32x4 accA, accB, t2 = {0.f, 0.f, 0.f, 0.f};
  {
    float d = dvA[node]; float sc = d * d;
    short4v v = *(const short4v*)(hA + (size_t)node * LDHA + c4);
    accA[0] = sc * bf2f((unsigned short)v[0]);
    accA[1] = sc * bf2f((unsigned short)v[1]);
    accA[2] = sc * bf2f((unsigned short)v[2]);
    accA[3] = sc * bf2f((unsigned short)v[3]);
    const int e1 = rpA[node + 1];
    int e = rpA[node];
    for (; e + 2 <= e1; e += 2) {
      int s0 = csA[e], s1 = csA[e + 1];
      float n0 = cnA[e], n1 = cnA[e + 1];
      short4v v0 = *(const short4v*)(hA + (size_t)s0 * LDHA + c4);
      short4v v1 = *(const short4v*)(hA + (size_t)s1 * LDHA + c4);
      accA[0] += n0 * bf2f((unsigned short)v0[0]); t2[0] += n1 * bf2f((unsigned short)v1[0]);
      accA[1] += n0 * bf2f((unsigned short)v0[1]); t2[1] += n1 * bf2f((unsigned short)v1[1]);
      accA[2] += n0 * bf2f((unsigned short)v0[2]); t2[2] += n1 * bf2f((unsigned short)v1[2]);
      accA[3] += n0 * bf2f((unsigned short)v0[3]); t2[3] += n1 * bf2f((unsigned short)v1[3]);
    }
    if (e < e1) {
      int s0 = csA[e]; float n0 = cnA[e];
      short4v v0 = *(const short4v*)(hA + (size_t)s0 * LDHA + c4);
      accA[0] += n0 * bf2f((unsigned short)v0[0]);
      accA[1] += n0 * bf2f((unsigned short)v0[1]);
      accA[2] += n0 * bf2f((unsigned short)v0[2]);
      accA[3] += n0 * bf2f((unsigned short)v0[3]);
    }
    #pragma unroll
    for (int i = 0; i < 4; i++) { accA[i] += t2[i]; t2[i] = 0.f; }
  }
  {
    float d = dvB[node]; float sc = d * d;
    short4v v = *(const short4v*)(hB + (size_t)node * LDHB + c4);
    accB[0] = sc * bf2f((unsigned short)v[0]);
    accB[1] = sc * bf2f((unsigned short)v[1]);
    accB[2] = sc * bf2f((unsigned short)v[2]);
    accB[3] = sc * bf2f((unsigned short)v[3]);
    const int e1 = rpB[node + 1];
    int e = rpB[node];
    for (; e + 2 <= e1; e += 2) {
      int s0 = csB[e], s1 = csB[e + 1];
      float n0 = cnB[e], n1 = cnB[e + 1];
      short4v v0 = *(const short4v*)(hB + (size_t)s0 * LDHB + c4);
      short4v v1 = *(const short4v*)(hB + (size_t)s1 * LDHB + c4);
      accB[0] += n0 * bf2f((unsigned short)v0[0]); t2[0] += n1 * bf2f((unsigned short)v1[0]);
      accB[1] += n0 * bf2f((unsigned short)v0[1]); t2[1] += n1 * bf2f((unsigned short)v1[1]);
      accB[2] += n0 * bf2f((unsigned short)v0[2]); t2[2] += n1 * bf2f((unsigned short)v1[2]);
      accB[3] += n0 * bf2f((unsigned short)v0[3]); t2[3] += n1 * bf2f((unsigned short)v1[3]);
    }
    if (e < e1) {
      int s0 = csB[e]; float n0 = cnB[e];
      short4v v0 = *(const short4v*)(hB + (size_t)s0 * LDHB + c4);
      accB[0] += n0 * bf2f((unsigned short)v0[0]);
      accB[1] += n0 * bf2f((unsigned short)v0[1]);
      accB[2] += n0 * bf2f((unsigned short)v0[2]);
      accB[3] += n0 * bf2f((unsigned short)v0[3]);
    }
    #pragma unroll
    for (int i = 0; i < 4; i++) accB[i] += t2[i];
  }
  f32x4 bvA = *(const f32x4*)(bA + c4);
  f32x4 bvB = *(const f32x4*)(bB + c4);
  float w = *wptr;
  size_t idx = (size_t)node * F + c4;
  f32x4 r;
  #pragma unroll
  for (int i = 0; i < 4; i++) {
    float va = accA[i] + bvA[i];
    float vb = accB[i] + bvB[i];
    if constexpr (DO_RELU) { va = fmaxf(va, 0.f); vb = fmaxf(vb, 0.f); }
    r[i] = w * va + (1.f - w) * vb;
  }
  if constexpr (OUT_BF16) {
    short4v o;
    o[0] = (short)f2bf(r[0]); o[1] = (short)f2bf(r[1]);
    o[2] = (short)f2bf(r[2]); o[3] = (short)f2bf(r[3]);
    *(short4v*)((unsigned short*)outp + idx) = o;
  } else {
    *(f32x4*)((float*)outp + idx) = r;
  }
}

// ---------------- host ----------------
extern "C" void kernel_launch(void* const* d_in, const int* in_sizes, int n_in,
                              void* d_out, int out_size, void* d_ws, size_t ws_size,
                              hipStream_t stream) {
  const float* gene  = (const float*)d_in[0];
  const float* img   = (const float*)d_in[1];
  const int* ei_ge = (const int*)d_in[2];   // integers arrive as int32
  const int* ei_sp = (const int*)d_in[3];
  const float* W_fc1 = (const float*)d_in[4];  const float* b_fc1 = (const float*)d_in[5];
  const float* W_fc2 = (const float*)d_in[6];  const float* b_fc2 = (const float*)d_in[7];
  const float* W_g11 = (const float*)d_in[8];  const float* b_g11 = (const float*)d_in[9];
  const float* W_g12 = (const float*)d_in[10]; const float* b_g12 = (const float*)d_in[11];
  const float* W_g21 = (const float*)d_in[12]; const float* b_g21 = (const float*)d_in[13];
  const float* W_g22 = (const float*)d_in[14]; const float* b_g22 = (const float*)d_in[15];
  const float* w1p   = (const float*)d_in[16];
  const float* w2p   = (const float*)d_in[17];

  const int Nn = 50000;
  const int E_ge = in_sizes[2] / 2;
  const int E_sp = in_sizes[3] / 2;
  const int NT_M = CDIV(Nn, 64);             // 782 M-tiles of 64
  const int PER  = CDIV(NT_M, 8);            // 98
  const int G1   = 8 * PER;                  // 784 (NT_N=1)
  const int G2   = 8 * PER * 2;              // 1568 (NT_N=2)

  char* ws = (char*)d_ws;
  size_t off = 0;
  auto alloc = [&](size_t bytes) -> void* {
    void* p = ws + off;
    off += (bytes + 255) & ~(size_t)255;
    return p;
  };

  unsigned short* Wt1  = (unsigned short*)alloc((size_t)512 * 3008 * 2);
  unsigned short* Wt2  = (unsigned short*)alloc((size_t)512 * 1024 * 2);
  unsigned short* Wt11 = (unsigned short*)alloc((size_t)256 * 512 * 2);
  unsigned short* Wt12 = (unsigned short*)alloc((size_t)256 * 512 * 2);
  unsigned short* WtC  = (unsigned short*)alloc((size_t)128 * 256 * 2);  // [W_g21 | W_g22] rows
  int*   deg_sp  = (int*)alloc((size_t)Nn * 4);
  int*   deg_ge  = (int*)alloc((size_t)Nn * 4);
  float* dinv_sp = (float*)alloc((size_t)Nn * 4);
  float* dinv_ge = (float*)alloc((size_t)Nn * 4);
  int*   rp_sp   = (int*)alloc((size_t)(Nn + 1) * 4);
  int*   rp_ge   = (int*)alloc((size_t)(Nn + 1) * 4);
  int*   cur_sp  = (int*)alloc((size_t)Nn * 4);
  int*   cur_ge  = (int*)alloc((size_t)Nn * 4);
  int*   csrc_sp = (int*)alloc((size_t)E_sp * 4);
  float* cnrm_sp = (float*)alloc((size_t)E_sp * 4);
  int*   csrc_ge = (int*)alloc((size_t)E_ge * 4);
  float* cnrm_ge = (float*)alloc((size_t)E_ge * 4);
  unsigned short* xbuf1 = (unsigned short*)alloc((size_t)Nn * 512 * 2);  // x1 / Xc
  unsigned short* xbuf2 = (unsigned short*)alloc((size_t)Nn * 512 * 2);  // x2
  unsigned short* tmpA  = (unsigned short*)alloc((size_t)Nn * 256 * 2);  // g11 out; later tmp2
  unsigned short* tmpB  = (unsigned short*)alloc((size_t)Nn * 256 * 2);  // g12 out
  unsigned short* Xc    = xbuf1;
  unsigned short* tmp2  = tmpA;
  (void)ws_size; (void)n_in; (void)out_size;

  // 1. weight transposes (bf16, K zero-padded)
  transpose_w<<<dim3(94, 16), 256, 0, stream>>>(W_fc1, Wt1, 3000, 512, 3008);
  transpose_w<<<dim3(32, 16), 256, 0, stream>>>(W_fc2, Wt2, 1024, 512, 1024);
  transpose_w<<<dim3(16, 8),  256, 0, stream>>>(W_g11, Wt11, 512, 256, 512);
  transpose_w<<<dim3(16, 8),  256, 0, stream>>>(W_g12, Wt12, 512, 256, 512);
  transpose_w<<<dim3(8, 2),   256, 0, stream>>>(W_g21, WtC, 256, 64, 256);
  transpose_w<<<dim3(8, 2),   256, 0, stream>>>(W_g22, WtC + (size_t)64 * 256, 256, 64, 256);

  // 2. graph prep (consolidated)
  prep_init<<<CDIV(Nn, 256), 256, 0, stream>>>(deg_sp, deg_ge, cur_sp, cur_ge, Nn);
  deg_hist_both<<<CDIV(E_sp + E_ge, 256), 256, 0, stream>>>(
      ei_sp, E_sp, deg_sp, ei_ge, E_ge, deg_ge, Nn);
  dinv_both<<<CDIV(Nn, 256), 256, 0, stream>>>(deg_sp, dinv_sp, deg_ge, dinv_ge, Nn);
  scan_rowptr_dual<<<2, 1024, 0, stream>>>(deg_sp, rp_sp, deg_ge, rp_ge, Nn);
  csr_fill_both<<<CDIV(E_sp + E_ge, 256), 256, 0, stream>>>(
      ei_sp, E_sp, rp_sp, cur_sp, dinv_sp, csrc_sp, cnrm_sp,
      ei_ge, E_ge, rp_ge, cur_ge, dinv_ge, csrc_ge, cnrm_ge, Nn);

  // 3. x1 = relu(gene @ W_fc1 + b) -> bf16   (r8-best: 64x256, NT_N=2, AMODE3)
  gemm7<64, 256, 256, 2, 3, true, true><<<G2, 256, 0, stream>>>(
      gene, Wt1, b_fc1, xbuf1, NT_M, Nn, 512, 3000, 3008);
  // 4. x2 = relu(img @ W_fc2 + b) -> bf16 (K=1024, no tail)
  gemm7<64, 256, 256, 2, 3, true, true><<<G2, 256, 0, stream>>>(
      img, Wt2, b_fc2, xbuf2, NT_M, Nn, 512, 1024, 1024);
  // 5. tmpA = x1 @ W_g11  (bf16 A via gl2lds, full-N=256)
  gemm7<64, 256, 256, 1, 1, false, false><<<G1, 256, 0, stream>>>(
      xbuf1, Wt11, nullptr, tmpA, NT_M, Nn, 256, 512, 512);
  // 6. tmpB = x2 @ W_g12
  gemm7<64, 256, 256, 1, 1, false, false><<<G1, 256, 0, stream>>>(
      xbuf2, Wt12, nullptr, tmpB, NT_M, Nn, 256, 512, 512);
  // 7. Xc = bf16( w1*relu(gcn_sp(tmpA)+b_g11) + (1-w1)*relu(gcn_ge(tmpB)+b_g12) )
  scatter_fused<256, 256, 256, true, true><<<Nn / 4, 256, 0, stream>>>(
      tmpA, tmpB, rp_sp, csrc_sp, cnrm_sp, dinv_sp, b_g11,
      rp_ge, csrc_ge, cnrm_ge, dinv_ge, b_g12, w1p, Xc, Nn);
  // 8. tmp2 = Xc @ [W_g21 | W_g22]  (N=128, one pass; tmp2 aliases tmpA)
  gemm7<64, 128, 256, 1, 1, false, false><<<G1, 256, 0, stream>>>(
      Xc, WtC, nullptr, tmp2, NT_M, Nn, 128, 256, 256);
  // 9. d_out = w2*(gcn_sp(tmp2[:,0:64])+b_g21) + (1-w2)*(gcn_ge(tmp2[:,64:128])+b_g22)
  scatter_fused<64, 128, 128, false, false><<<Nn / 16, 256, 0, stream>>>(
      tmp2, tmp2 + 64, rp_sp, csrc_sp, cnrm_sp, dinv_sp, b_g21,
      rp_ge, csrc_ge, cnrm_ge, dinv_ge, b_g22, w2p, d_out, Nn);
}

// Round 15
// 736.113 us; speedup vs baseline: 1.8087x; 1.1359x over previous
//
#include <hip/hip_runtime.h>
#include <hip/hip_bf16.h>
#include <stdint.h>

typedef __attribute__((ext_vector_type(4))) float f32x4;
typedef __attribute__((ext_vector_type(8))) short short8;
typedef __attribute__((ext_vector_type(4))) short short4v;

#define CDIV(a, b) (((a) + (b) - 1) / (b))

__device__ __forceinline__ unsigned short f2bf(float x) {
  union { float f; unsigned int u; } c; c.f = x;
  unsigned int r = c.u + 0x7FFFu + ((c.u >> 16) & 1u);   // round-to-nearest-even
  return (unsigned short)(r >> 16);
}
__device__ __forceinline__ unsigned short f2bf_hw(float x) {
  __hip_bfloat16 h = __float2bfloat16(x);                // pairs fuse into v_cvt_pk_bf16_f32
  unsigned short u; __builtin_memcpy(&u, &h, 2); return u;
}
__device__ __forceinline__ float bf2f(unsigned short b) {
  union { unsigned int u; float f; } c; c.u = (unsigned int)b << 16; return c.f;
}

// async global->LDS, 16B per lane; LDS dest must be wave-uniform base + lane*16 (linear)
__device__ __forceinline__ void gl2lds16(const void* g, void* lds) {
  __builtin_amdgcn_global_load_lds(
      reinterpret_cast<const __attribute__((address_space(1))) unsigned int*>(
          reinterpret_cast<uintptr_t>(g)),
      reinterpret_cast<__attribute__((address_space(3))) unsigned int*>(
          reinterpret_cast<uintptr_t>(lds)),
      16, 0, 0);
}

// ---------------- weight transpose: W[K][N] f32 -> Wt[N][Kpad] bf16, zero-padded ----------------
__global__ void transpose_w(const float* __restrict__ W, unsigned short* __restrict__ Wt,
                            int K, int N, int Kpad) {
  __shared__ float tile[32][33];
  int kb = blockIdx.x * 32, nb = blockIdx.y * 32;
  int tx = threadIdx.x & 31, ty = threadIdx.x >> 5;  // 256 threads = 32x8
  for (int r = ty; r < 32; r += 8) {
    int k = kb + r, n = nb + tx;
    tile[r][tx] = (k < K && n < N) ? W[(size_t)k * N + n] : 0.f;
  }
  __syncthreads();
  for (int r = ty; r < 32; r += 8) {
    int n = nb + r, k = kb + tx;
    if (n < N && k < Kpad) Wt[(size_t)n * Kpad + k] = f2bf(tile[tx][r]);
  }
}

// ---------------- graph prep (consolidated: both graphs per launch) ----------------
__global__ void prep_init(int* __restrict__ dA, int* __restrict__ dB,
                          int* __restrict__ cA, int* __restrict__ cB, int n) {
  int i = blockIdx.x * blockDim.x + threadIdx.x;
  if (i < n) { dA[i] = 1; dB[i] = 1; cA[i] = 0; cB[i] = 0; }   // deg=1 (self-loop), cursor=0
}

__global__ void deg_hist_both(const int* __restrict__ eiA, int EA, int* __restrict__ degA,
                              const int* __restrict__ eiB, int EB, int* __restrict__ degB, int n) {
  int e = blockIdx.x * blockDim.x + threadIdx.x;
  if (e < EA) {
    unsigned int d = (unsigned int)eiA[(size_t)EA + e];
    if (d < (unsigned int)n) atomicAdd(&degA[d], 1);
  } else if (e < EA + EB) {
    int e2 = e - EA;
    unsigned int d = (unsigned int)eiB[(size_t)EB + e2];
    if (d < (unsigned int)n) atomicAdd(&degB[d], 1);
  }
}

__global__ void dinv_both(const int* __restrict__ dA, float* __restrict__ vA,
                          const int* __restrict__ dB, float* __restrict__ vB, int n) {
  int i = blockIdx.x * blockDim.x + threadIdx.x;
  if (i < n) { vA[i] = rsqrtf((float)dA[i]); vB[i] = rsqrtf((float)dB[i]); }
}

// exclusive scan of (deg-1) -> row_ptr[0..n]; blockIdx.x selects graph
__global__ void scan_rowptr_dual(const int* __restrict__ degA, int* __restrict__ rpA,
                                 const int* __restrict__ degB, int* __restrict__ rpB, int n) {
  const int* deg = (blockIdx.x == 0) ? degA : degB;
  int* rp = (blockIdx.x == 0) ? rpA : rpB;
  __shared__ int wsum[16];
  __shared__ int carry_s;
  const int tid = threadIdx.x, lane = tid & 63, w = tid >> 6;
  if (tid == 0) carry_s = 0;
  __syncthreads();
  for (int base = 0; base < n; base += 1024) {
    int i = base + tid;
    int d = (i < n) ? (deg[i] - 1) : 0;
    int v = d;
    #pragma unroll
    for (int off = 1; off < 64; off <<= 1) {
      int t = __shfl_up(v, off, 64);
      if (lane >= off) v += t;
    }
    if (lane == 63) wsum[w] = v;
    __syncthreads();
    int carry = carry_s;
    if (w == 0) {
      int s = (lane < 16) ? wsum[lane] : 0;
      #pragma unroll
      for (int off = 1; off < 16; off <<= 1) {
        int t = __shfl_up(s, off, 64);
        if (lane >= off) s += t;
      }
      if (lane < 16) wsum[lane] = s;
    }
    __syncthreads();
    int woff = (w > 0) ? wsum[w - 1] : 0;
    if (i < n) rp[i] = carry + woff + v - d;
    if (tid == 0) carry_s = carry + wsum[15];
    __syncthreads();
  }
  if (threadIdx.x == 0) rp[n] = carry_s;
}

__global__ void csr_fill_both(const int* __restrict__ eiA, int EA, const int* __restrict__ rpA,
                              int* __restrict__ curA, const float* __restrict__ dvA,
                              int* __restrict__ csA, float* __restrict__ cnA,
                              const int* __restrict__ eiB, int EB, const int* __restrict__ rpB,
                              int* __restrict__ curB, const float* __restrict__ dvB,
                              int* __restrict__ csB, float* __restrict__ cnB, int n) {
  int e = blockIdx.x * blockDim.x + threadIdx.x;
  if (e < EA) {
    unsigned int s = (unsigned int)eiA[e];
    unsigned int d = (unsigned int)eiA[(size_t)EA + e];
    if (s < (unsigned int)n && d < (unsigned int)n) {
      int pos = rpA[d] + atomicAdd(&curA[d], 1);
      csA[pos] = (int)s;
      cnA[pos] = dvA[s] * dvA[d];
    }
  } else if (e < EA + EB) {
    int e2 = e - EA;
    unsigned int s = (unsigned int)eiB[e2];
    unsigned int d = (unsigned int)eiB[(size_t)EB + e2];
    if (s < (unsigned int)n && d < (unsigned int)n) {
      int pos = rpB[d] + atomicAdd(&curB[d], 1);
      csB[pos] = (int)s;
      cnB[pos] = dvB[s] * dvB[d];
    }
  }
}

// ---------------- gemm_pair: TWO independent GEMMs, CONCATENATED block ranges ----------------
// Blocks [0,split) = job0, [split,..) = job1 (split % 8 == 0 so bid%8 == HW XCD is
// preserved for both jobs -> XCD-grouped locality intact, unlike interleaved r12).
// Overlap region gives 2 independent barrier domains per CU (latency hiding).
// Body = r8-proven gemm7. AMODE 1: A bf16 via gl2lds. AMODE 3: A f32 RAW via gl2lds,
// bf16 cvt at fragment read; K-tail reg-staged zero-masked (K%4==0).
template<int BM, int BN, int TH, int NT_N, int AMODE, bool ADD_BIAS, bool DO_RELU>
__global__ __launch_bounds__(TH, 2)
void gemm_pair(const void* __restrict__ A0, const unsigned short* __restrict__ Bt0,
               const float* __restrict__ b0, unsigned short* __restrict__ C0, int K0, int Kp0,
               const void* __restrict__ A1, const unsigned short* __restrict__ Bt1,
               const float* __restrict__ b1, unsigned short* __restrict__ C1, int K1, int Kp1,
               int split, int NT_M, int M, int N) {
  constexpr int BK = 64;
  constexpr int WN = TH / 64;
  constexpr int WCOLS = BN / WN;
  constexpr int FM = BM / 16, FN = WCOLS / 16;
  constexpr int BIT  = (BN * 8) / TH;
  constexpr int AIT1 = (BM * 8) / TH;
  constexpr int AIT3 = (BM * 16) / TH;
  constexpr int LOGN = (NT_N == 4) ? 2 : (NT_N == 2 ? 1 : 0);

  const int bid0 = blockIdx.x;
  const bool j1 = (bid0 >= split);
  const int bid = j1 ? (bid0 - split) : bid0;
  const void* Av = j1 ? A1 : A0;
  const unsigned short* Bt = j1 ? Bt1 : Bt0;
  const float* bias = j1 ? b1 : b0;
  unsigned short* C = j1 ? C1 : C0;
  const int K = j1 ? K1 : K0;
  const int Kpad = j1 ? Kp1 : Kp0;

  const int xcd = bid & 7, j = bid >> 3;
  const int per = (NT_M + 7) >> 3;
  const int mt = xcd * per + (j >> LOGN);
  const int nt = j & (NT_N - 1);
  if (mt >= NT_M) return;
  const int gm = mt * BM, gn = nt * BN;

  constexpr int ABYTES = (AMODE == 3) ? BM * BK * 4 : BM * BK * 2;
  __shared__ __align__(16) char AldsRaw[ABYTES];
  __shared__ __align__(16) unsigned short Blds[BN * BK];

  const int tid = threadIdx.x;
  const int wid = tid >> 6, lane = tid & 63;
  const int kg = lane >> 4, lr = lane & 15;
  const int sx = lr & 7;

  f32x4 acc[FM][FN] = {};

  const int nkt = Kpad / BK;
  for (int kt = 0; kt < nkt; ++kt) {
    const int k0 = kt * BK;
    // ---- stage A ----
    if constexpr (AMODE == 1) {
      const unsigned short* A = (const unsigned short*)Av;
      unsigned short* Alds = (unsigned short*)AldsRaw;
      #pragma unroll
      for (int it = 0; it < AIT1; ++it) {
        int q = it * TH + tid;
        int r = q >> 3, s = q & 7;
        int grow = gm + r; if (grow > M - 1) grow = M - 1;
        gl2lds16(A + (size_t)grow * K + k0 + ((s ^ (r & 7)) << 3), &Alds[q * 8]);
      }
    } else {  // AMODE 3: raw f32, 16 slots/row, swizzled source
      const float* A = (const float*)Av;
      float* Af = (float*)AldsRaw;
      if (k0 + BK <= K) {
        #pragma unroll
        for (int it = 0; it < AIT3; ++it) {
          int q = it * TH + tid;
          int r = q >> 4, s = q & 15;
          int grow = gm + r; if (grow > M - 1) grow = M - 1;
          gl2lds16(A + (size_t)grow * K + k0 + ((s ^ (r & 15)) << 2), &Af[q * 4]);
        }
      } else {  // tail (K%4==0): reg-staged, zero-masked
        #pragma unroll
        for (int it = 0; it < AIT3; ++it) {
          int q = it * TH + tid;
          int r = q >> 4, s = q & 15;
          int grow = gm + r; if (grow > M - 1) grow = M - 1;
          int kbase = k0 + ((s ^ (r & 15)) << 2);
          f32x4 v = {0.f, 0.f, 0.f, 0.f};
          if (kbase + 4 <= K) v = *(const f32x4*)(A + (size_t)grow * K + kbase);
          *(f32x4*)(&Af[q * 4]) = v;
        }
      }
    }
    // ---- stage B via gl2lds (linear dest, inverse-swizzled source) ----
    #pragma unroll
    for (int it = 0; it < BIT; ++it) {
      int q = it * TH + tid;
      int r = q >> 3, s = q & 7;
      gl2lds16(Bt + (size_t)(gn + r) * Kpad + k0 + ((s ^ (r & 7)) << 3), &Blds[q * 8]);
    }
    __syncthreads();
    // ---- fragments + MFMA (2 K-slices of 32) ----
    #pragma unroll
    for (int ks = 0; ks < 2; ++ks) {
      const int k8 = ks * 4 + kg;
      short8 af[FM];
      #pragma unroll
      for (int m = 0; m < FM; m++) {
        int r = m * 16 + lr;                 // r & 15 == lr
        if constexpr (AMODE == 1) {
          const unsigned short* Alds = (const unsigned short*)AldsRaw;
          af[m] = *(const short8*)(&Alds[(r * 8 + (k8 ^ sx)) * 8]);
        } else {
          const float* Af = (const float*)AldsRaw;
          int s0 = (2 * k8) ^ lr, s1 = (2 * k8 + 1) ^ lr;
          f32x4 lo = *(const f32x4*)(Af + r * 64 + s0 * 4);
          f32x4 hi = *(const f32x4*)(Af + r * 64 + s1 * 4);
          #pragma unroll
          for (int i = 0; i < 4; i++) {
            af[m][i]     = (short)f2bf_hw(lo[i]);
            af[m][i + 4] = (short)f2bf_hw(hi[i]);
          }
        }
      }
      #pragma unroll
      for (int n2 = 0; n2 < FN; n2++) {
        int cc = wid * WCOLS + n2 * 16 + lr;
        short8 bq = *(const short8*)(&Blds[(cc * 8 + (k8 ^ sx)) * 8]);
        #pragma unroll
        for (int m = 0; m < FM; m++)
          acc[m][n2] = __builtin_amdgcn_mfma_f32_16x16x32_bf16(af[m], bq, acc[m][n2], 0, 0, 0);
      }
    }
    __syncthreads();
  }
  // ---- epilogue: C/D layout col=lane&15, row=(lane>>4)*4+reg ----
  #pragma unroll
  for (int m = 0; m < FM; m++) {
    #pragma unroll
    for (int jj = 0; jj < 4; jj++) {
      int grow = gm + m * 16 + kg * 4 + jj;
      if (grow < M) {
        #pragma unroll
        for (int n2 = 0; n2 < FN; n2++) {
          int gcol = gn + wid * WCOLS + n2 * 16 + lr;
          float v = acc[m][n2][jj];
          if constexpr (ADD_BIAS) v += bias[gcol];
          if constexpr (DO_RELU) v = fmaxf(v, 0.f);
          C[(size_t)grow * N + gcol] = f2bf(v);
        }
      }
    }
  }
}

// ---------------- single-job GEMM (final layer), r8-proven config ----------------
template<int BM, int BN, int TH, int NT_N, int AMODE, bool ADD_BIAS, bool DO_RELU>
__global__ __launch_bounds__(TH, 2)
void gemm7(const void* __restrict__ Av, const unsigned short* __restrict__ Bt,
           const float* __restrict__ bias, unsigned short* __restrict__ C,
           int NT_M, int M, int N, int K, int Kpad) {
  constexpr int BK = 64;
  constexpr int WN = TH / 64;
  constexpr int WCOLS = BN / WN;
  constexpr int FM = BM / 16, FN = WCOLS / 16;
  constexpr int BIT  = (BN * 8) / TH;
  constexpr int AIT1 = (BM * 8) / TH;
  constexpr int LOGN = (NT_N == 2) ? 1 : 0;

  const int bid = blockIdx.x;
  const int xcd = bid & 7, j = bid >> 3;
  const int per = (NT_M + 7) >> 3;
  const int mt = xcd * per + (j >> LOGN);
  const int nt = j & (NT_N - 1);
  if (mt >= NT_M) return;
  const int gm = mt * BM, gn = nt * BN;

  __shared__ __align__(16) unsigned short Alds[BM * BK];
  __shared__ __align__(16) unsigned short Blds[BN * BK];

  const int tid = threadIdx.x;
  const int wid = tid >> 6, lane = tid & 63;
  const int kg = lane >> 4, lr = lane & 15;
  const int sx = lr & 7;

  f32x4 acc[FM][FN] = {};

  const int nkt = Kpad / BK;
  for (int kt = 0; kt < nkt; ++kt) {
    const int k0 = kt * BK;
    const unsigned short* A = (const unsigned short*)Av;
    #pragma unroll
    for (int it = 0; it < AIT1; ++it) {
      int q = it * TH + tid;
      int r = q >> 3, s = q & 7;
      int grow = gm + r; if (grow > M - 1) grow = M - 1;
      gl2lds16(A + (size_t)grow * K + k0 + ((s ^ (r & 7)) << 3), &Alds[q * 8]);
    }
    #pragma unroll
    for (int it = 0; it < BIT; ++it) {
      int q = it * TH + tid;
      int r = q >> 3, s = q & 7;
      gl2lds16(Bt + (size_t)(gn + r) * Kpad + k0 + ((s ^ (r & 7)) << 3), &Blds[q * 8]);
    }
    __syncthreads();
    #pragma unroll
    for (int ks = 0; ks < 2; ++ks) {
      const int k8 = ks * 4 + kg;
      short8 af[FM];
      #pragma unroll
      for (int m = 0; m < FM; m++) {
        int r = m * 16 + lr;
        af[m] = *(const short8*)(&Alds[(r * 8 + (k8 ^ sx)) * 8]);
      }
      #pragma unroll
      for (int n2 = 0; n2 < FN; n2++) {
        int cc = wid * WCOLS + n2 * 16 + lr;
        short8 bq = *(const short8*)(&Blds[(cc * 8 + (k8 ^ sx)) * 8]);
        #pragma unroll
        for (int m = 0; m < FM; m++)
          acc[m][n2] = __builtin_amdgcn_mfma_f32_16x16x32_bf16(af[m], bq, acc[m][n2], 0, 0, 0);
      }
    }
    __syncthreads();
  }
  #pragma unroll
  for (int m = 0; m < FM; m++) {
    #pragma unroll
    for (int jj = 0; jj < 4; jj++) {
      int grow = gm + m * 16 + kg * 4 + jj;
      if (grow < M) {
        #pragma unroll
        for (int n2 = 0; n2 < FN; n2++) {
          int gcol = gn + wid * WCOLS + n2 * 16 + lr;
          float v = acc[m][n2][jj];
          if constexpr (ADD_BIAS) v += bias[gcol];
          if constexpr (DO_RELU) v = fmaxf(v, 0.f);
          C[(size_t)grow * N + gcol] = f2bf(v);
        }
      }
    }
  }
}

// ---------------- per-graph GCN gather: 4-way unrolled edge loop ----------------
template<int LDH>
__device__ __forceinline__ f32x4 gcn_gather(const unsigned short* __restrict__ h,
                                            const int* __restrict__ rp,
                                            const int* __restrict__ cs,
                                            const float* __restrict__ cn,
                                            const float* __restrict__ dv,
                                            int node, int c4) {
  float d = dv[node];
  float sc = d * d;
  f32x4 a0, a1 = {0.f,0.f,0.f,0.f}, a2 = {0.f,0.f,0.f,0.f}, a3 = {0.f,0.f,0.f,0.f};
  {
    short4v v = *(const short4v*)(h + (size_t)node * LDH + c4);
    a0[0] = sc * bf2f((unsigned short)v[0]);
    a0[1] = sc * bf2f((unsigned short)v[1]);
    a0[2] = sc * bf2f((unsigned short)v[2]);
    a0[3] = sc * bf2f((unsigned short)v[3]);
  }
  int e = rp[node];
  const int e1 = rp[node + 1];
  for (; e + 4 <= e1; e += 4) {               // 4 independent gathers in flight
    int s0 = cs[e], s1 = cs[e+1], s2 = cs[e+2], s3 = cs[e+3];
    float n0 = cn[e], n1 = cn[e+1], n2 = cn[e+2], n3 = cn[e+3];
    short4v v0 = *(const short4v*)(h + (size_t)s0 * LDH + c4);
    short4v v1 = *(const short4v*)(h + (size_t)s1 * LDH + c4);
    short4v v2 = *(const short4v*)(h + (size_t)s2 * LDH + c4);
    short4v v3 = *(const short4v*)(h + (size_t)s3 * LDH + c4);
    #pragma unroll
    for (int i = 0; i < 4; i++) {
      a0[i] += n0 * bf2f((unsigned short)v0[i]);
      a1[i] += n1 * bf2f((unsigned short)v1[i]);
      a2[i] += n2 * bf2f((unsigned short)v2[i]);
      a3[i] += n3 * bf2f((unsigned short)v3[i]);
    }
  }
  for (; e < e1; ++e) {
    int s0 = cs[e]; float n0 = cn[e];
    short4v v0 = *(const short4v*)(h + (size_t)s0 * LDH + c4);
    #pragma unroll
    for (int i = 0; i < 4; i++) a0[i] += n0 * bf2f((unsigned short)v0[i]);
  }
  #pragma unroll
  for (int i = 0; i < 4; i++) a0[i] += a1[i] + a2[i] + a3[i];
  return a0;
}

// ---------------- fused dual-graph GCN scatter ----------------
// out = w * act(gcnA(hA)+bA) + (1-w) * act(gcnB(hB)+bB), act = relu or identity.
template<int F, int LDHA, int LDHB, bool DO_RELU, bool OUT_BF16>
__global__ __launch_bounds__(256)
void scatter_fused(const unsigned short* __restrict__ hA, const unsigned short* __restrict__ hB,
                   const int* __restrict__ rpA, const int* __restrict__ csA,
                   const float* __restrict__ cnA, const float* __restrict__ dvA,
                   const float* __restrict__ bA,
                   const int* __restrict__ rpB, const int* __restrict__ csB,
                   const float* __restrict__ cnB, const float* __restrict__ dvB,
                   const float* __restrict__ bB,
                   const float* __restrict__ wptr, void* __restrict__ outp, int n) {
  constexpr int TPN = F / 4;
  const int tid = threadIdx.x;
  const int node = blockIdx.x * (256 / TPN) + tid / TPN;
  const int c4 = (tid % TPN) * 4;
  if (node >= n) return;

  f32x4 accA = gcn_gather<LDHA>(hA, rpA, csA, cnA, dvA, node, c4);
  f32x4 accB = gcn_gather<LDHB>(hB, rpB, csB, cnB, dvB, node, c4);

  f32x4 bvA = *(const f32x4*)(bA + c4);
  f32x4 bvB = *(const f32x4*)(bB + c4);
  float w = *wptr;
  size_t idx = (size_t)node * F + c4;
  f32x4 r;
  #pragma unroll
  for (int i = 0; i < 4; i++) {
    float va = accA[i] + bvA[i];
    float vb = accB[i] + bvB[i];
    if constexpr (DO_RELU) { va = fmaxf(va, 0.f); vb = fmaxf(vb, 0.f); }
    r[i] = w * va + (1.f - w) * vb;
  }
  if constexpr (OUT_BF16) {
    short4v o;
    o[0] = (short)f2bf(r[0]); o[1] = (short)f2bf(r[1]);
    o[2] = (short)f2bf(r[2]); o[3] = (short)f2bf(r[3]);
    *(short4v*)((unsigned short*)outp + idx) = o;
  } else {
    *(f32x4*)((float*)outp + idx) = r;
  }
}

// ---------------- host ----------------
extern "C" void kernel_launch(void* const* d_in, const int* in_sizes, int n_in,
                              void* d_out, int out_size, void* d_ws, size_t ws_size,
                              hipStream_t stream) {
  const float* gene  = (const float*)d_in[0];
  const float* img   = (const float*)d_in[1];
  const int* ei_ge = (const int*)d_in[2];   // integers arrive as int32
  const int* ei_sp = (const int*)d_in[3];
  const float* W_fc1 = (const float*)d_in[4];  const float* b_fc1 = (const float*)d_in[5];
  const float* W_fc2 = (const float*)d_in[6];  const float* b_fc2 = (const float*)d_in[7];
  const float* W_g11 = (const float*)d_in[8];  const float* b_g11 = (const float*)d_in[9];
  const float* W_g12 = (const float*)d_in[10]; const float* b_g12 = (const float*)d_in[11];
  const float* W_g21 = (const float*)d_in[12]; const float* b_g21 = (const float*)d_in[13];
  const float* W_g22 = (const float*)d_in[14]; const float* b_g22 = (const float*)d_in[15];
  const float* w1p   = (const float*)d_in[16];
  const float* w2p   = (const float*)d_in[17];

  const int Nn = 50000;
  const int E_ge = in_sizes[2] / 2;
  const int E_sp = in_sizes[3] / 2;
  const int NT_M = CDIV(Nn, 64);             // 782 M-tiles of 64
  const int PER  = CDIV(NT_M, 8);            // 98
  const int G1   = 8 * PER;                  // 784 (NT_N=1), % 8 == 0
  const int G2   = 8 * PER * 2;              // 1568 (NT_N=2), % 8 == 0

  char* ws = (char*)d_ws;
  size_t off = 0;
  auto alloc = [&](size_t bytes) -> void* {
    void* p = ws + off;
    off += (bytes + 255) & ~(size_t)255;
    return p;
  };

  unsigned short* Wt1  = (unsigned short*)alloc((size_t)512 * 3008 * 2);
  unsigned short* Wt2  = (unsigned short*)alloc((size_t)512 * 1024 * 2);
  unsigned short* Wt11 = (unsigned short*)alloc((size_t)256 * 512 * 2);
  unsigned short* Wt12 = (unsigned short*)alloc((size_t)256 * 512 * 2);
  unsigned short* WtC  = (unsigned short*)alloc((size_t)128 * 256 * 2);  // [W_g21 | W_g22] rows
  int*   deg_sp  = (int*)alloc((size_t)Nn * 4);
  int*   deg_ge  = (int*)alloc((size_t)Nn * 4);
  float* dinv_sp = (float*)alloc((size_t)Nn * 4);
  float* dinv_ge = (float*)alloc((size_t)Nn * 4);
  int*   rp_sp   = (int*)alloc((size_t)(Nn + 1) * 4);
  int*   rp_ge   = (int*)alloc((size_t)(Nn + 1) * 4);
  int*   cur_sp  = (int*)alloc((size_t)Nn * 4);
  int*   cur_ge  = (int*)alloc((size_t)Nn * 4);
  int*   csrc_sp = (int*)alloc((size_t)E_sp * 4);
  float* cnrm_sp = (float*)alloc((size_t)E_sp * 4);
  int*   csrc_ge = (int*)alloc((size_t)E_ge * 4);
  float* cnrm_ge = (float*)alloc((size_t)E_ge * 4);
  unsigned short* xbuf1 = (unsigned short*)alloc((size_t)Nn * 512 * 2);  // x1 / Xc
  unsigned short* xbuf2 = (unsigned short*)alloc((size_t)Nn * 512 * 2);  // x2
  unsigned short* tmpA  = (unsigned short*)alloc((size_t)Nn * 256 * 2);  // g11 out; later tmp2
  unsigned short* tmpB  = (unsigned short*)alloc((size_t)Nn * 256 * 2);  // g12 out
  unsigned short* Xc    = xbuf1;
  unsigned short* tmp2  = tmpA;
  (void)ws_size; (void)n_in; (void)out_size;

  // 1. weight transposes (bf16, K zero-padded)
  transpose_w<<<dim3(94, 16), 256, 0, stream>>>(W_fc1, Wt1, 3000, 512, 3008);
  transpose_w<<<dim3(32, 16), 256, 0, stream>>>(W_fc2, Wt2, 1024, 512, 1024);
  transpose_w<<<dim3(16, 8),  256, 0, stream>>>(W_g11, Wt11, 512, 256, 512);
  transpose_w<<<dim3(16, 8),  256, 0, stream>>>(W_g12, Wt12, 512, 256, 512);
  transpose_w<<<dim3(8, 2),   256, 0, stream>>>(W_g21, WtC, 256, 64, 256);
  transpose_w<<<dim3(8, 2),   256, 0, stream>>>(W_g22, WtC + (size_t)64 * 256, 256, 64, 256);

  // 2. graph prep (consolidated)
  prep_init<<<CDIV(Nn, 256), 256, 0, stream>>>(deg_sp, deg_ge, cur_sp, cur_ge, Nn);
  deg_hist_both<<<CDIV(E_sp + E_ge, 256), 256, 0, stream>>>(
      ei_sp, E_sp, deg_sp, ei_ge, E_ge, deg_ge, Nn);
  dinv_both<<<CDIV(Nn, 256), 256, 0, stream>>>(deg_sp, dinv_sp, deg_ge, dinv_ge, Nn);
  scan_rowptr_dual<<<2, 1024, 0, stream>>>(deg_sp, rp_sp, deg_ge, rp_ge, Nn);
  csr_fill_both<<<CDIV(E_sp + E_ge, 256), 256, 0, stream>>>(
      ei_sp, E_sp, rp_sp, cur_sp, dinv_sp, csrc_sp, cnrm_sp,
      ei_ge, E_ge, rp_ge, cur_ge, dinv_ge, csrc_ge, cnrm_ge, Nn);

  // 3. FC1 + FC2 in one launch, CONCATENATED ranges (XCD mapping preserved):
  //    x1 = relu(gene@W1+b) ; x2 = relu(img@W2+b)
  gemm_pair<64, 256, 256, 2, 3, true, true><<<2 * G2, 256, 0, stream>>>(
      gene, Wt1, b_fc1, xbuf1, 3000, 3008,
      img,  Wt2, b_fc2, xbuf2, 1024, 1024,
      G2, NT_M, Nn, 512);
  // 4. mids in one launch: tmpA = x1 @ W_g11 ; tmpB = x2 @ W_g12
  gemm_pair<64, 256, 256, 1, 1, false, false><<<2 * G1, 256, 0, stream>>>(
      xbuf1, Wt11, nullptr, tmpA, 512, 512,
      xbuf2, Wt12, nullptr, tmpB, 512, 512,
      G1, NT_M, Nn, 256);
  // 5. Xc = bf16( w1*relu(gcn_sp(tmpA)+b_g11) + (1-w1)*relu(gcn_ge(tmpB)+b_g12) )
  scatter_fused<256, 256, 256, true, true><<<Nn / 4, 256, 0, stream>>>(
      tmpA, tmpB, rp_sp, csrc_sp, cnrm_sp, dinv_sp, b_g11,
      rp_ge, csrc_ge, cnrm_ge, dinv_ge, b_g12, w1p, Xc, Nn);
  // 6. tmp2 = Xc @ [W_g21 | W_g22]  (N=128, one pass; tmp2 aliases tmpA)
  gemm7<64, 128, 256, 1, 1, false, false><<<G1, 256, 0, stream>>>(
      Xc, WtC, nullptr, tmp2, NT_M, Nn, 128, 256, 256);
  // 7. d_out = w2*(gcn_sp(tmp2[:,0:64])+b_g21) + (1-w2)*(gcn_ge(tmp2[:,64:128])+b_g22)
  scatter_fused<64, 128, 128, false, false><<<Nn / 16, 256, 0, stream>>>(
      tmp2, tmp2 + 64, rp_sp, csrc_sp, cnrm_sp, dinv_sp, b_g21,
      rp_ge, csrc_ge, cnrm_ge, dinv_ge, b_g22, w2p, d_out, Nn);
}